// Round 18
// baseline (478.972 us; speedup 1.0000x reference)
//
#include <hip/hip_runtime.h>
#include <hip/hip_bf16.h>

#define NN 50000
#define EE 600000
#define DD 128
#define RR 7
#define SS 8            // R + self-loop slot
#define GG 32
#define NSEG (NN * RR)  // 350000 CSR segments
#define NB1 ((NSEG + 1023) / 1024)   // 342 scan blocks

typedef float f32x4 __attribute__((ext_vector_type(4)));
typedef float f32x2 __attribute__((ext_vector_type(2)));
typedef short short8 __attribute__((ext_vector_type(8)));
typedef unsigned short u16x8 __attribute__((ext_vector_type(8)));

static __device__ __forceinline__ unsigned short f2bf(float f) {
    union { float f; unsigned u; } v; v.f = f;
    unsigned r = v.u + 0x7fff + ((v.u >> 16) & 1);
    return (unsigned short)(r >> 16);
}
static __device__ __forceinline__ float bf2f(unsigned short u) {
    union { unsigned u; float f; } v; v.u = ((unsigned)u) << 16;
    return v.f;
}

// ---- weights prep: Wt2[j=(slot,dout)][k=din] bf16; bias = lin_b + sl_b ----
__global__ void prep_w2(const float* __restrict__ lin_w, const float* __restrict__ sl_w,
                        const float* __restrict__ lin_b, const float* __restrict__ sl_b,
                        unsigned short* __restrict__ Wt2, float* __restrict__ bias) {
    int idx = blockIdx.x * 256 + threadIdx.x;   // 131072
    if (idx < DD) bias[idx] = lin_b[idx] + sl_b[idx];
    if (idx >= 1024 * DD) return;
    int j = idx >> 7;                  // output col: slot*128 + dout
    int k = idx & 127;                 // din
    int slot = j >> 7, dout = j & 127;
    float w = (slot < 7) ? lin_w[(slot * DD + k) * DD + dout] : sl_w[k * DD + dout];
    Wt2[(size_t)j * DD + k] = f2bf(w);
}

// ---------------- CSR build ----------------
__global__ void zero_ints(int* __restrict__ p, int n) {
    int i = blockIdx.x * 256 + threadIdx.x;
    if (i < n) p[i] = 0;
}

__global__ void hist(const int* __restrict__ node_out, const int* __restrict__ rel,
                     int* __restrict__ counts) {
    int e = blockIdx.x * 256 + threadIdx.x;
    if (e >= EE) return;
    atomicAdd(&counts[node_out[e] * RR + rel[e]], 1);
}

__global__ __launch_bounds__(256) void scan1(const int* __restrict__ counts,
                                             int* __restrict__ start, int* __restrict__ bsum) {
    __shared__ int s[256];
    int tid = threadIdx.x;
    int base = blockIdx.x * 1024 + tid * 4;
    int v[4], sum = 0;
    #pragma unroll
    for (int j = 0; j < 4; ++j) {
        v[j] = (base + j < NSEG) ? counts[base + j] : 0;
        sum += v[j];
    }
    s[tid] = sum; __syncthreads();
    for (int off = 1; off < 256; off <<= 1) {
        int t = (tid >= off) ? s[tid - off] : 0;
        __syncthreads();
        s[tid] += t;
        __syncthreads();
    }
    int run = s[tid] - sum;
    if (tid == 255) bsum[blockIdx.x] = s[255];
    #pragma unroll
    for (int j = 0; j < 4; ++j) {
        if (base + j < NSEG) { start[base + j] = run; run += v[j]; }
    }
}

__global__ __launch_bounds__(512) void scan2(int* __restrict__ bsum) {
    __shared__ int s[512];
    int tid = threadIdx.x;
    int v = (tid < NB1) ? bsum[tid] : 0;
    s[tid] = v; __syncthreads();
    for (int off = 1; off < 512; off <<= 1) {
        int t = (tid >= off) ? s[tid - off] : 0;
        __syncthreads();
        s[tid] += t;
        __syncthreads();
    }
    if (tid < NB1) bsum[tid] = s[tid] - v;
}

__global__ void scan3(const int* __restrict__ start, const int* __restrict__ bsum,
                      const int* __restrict__ counts, int2* __restrict__ segd) {
    int i = blockIdx.x * 256 + threadIdx.x;
    if (i < NSEG) segd[i] = make_int2(start[i] + bsum[i >> 10], counts[i]);
}

// record: x = (rel << 16) | node_in, y = weight bits
__global__ void fill(const int* __restrict__ node_in, const int* __restrict__ node_out,
                     const int* __restrict__ rel, const float* __restrict__ ew,
                     const int2* __restrict__ segd, int* __restrict__ cursor,
                     int2* __restrict__ edges) {
    int e = blockIdx.x * 256 + threadIdx.x;
    if (e >= EE) return;
    int seg = node_out[e] * RR + rel[e];
    int pos = segd[seg].x + atomicAdd(&cursor[seg], 1);
    edges[pos] = make_int2((rel[e] << 16) | node_in[e], __float_as_int(ew[e]));
}

// layer-0 bf16 shadow of x.  EXACTLY NN*32 threads (6250 blocks).
__global__ void init_hb(const float* __restrict__ x, unsigned short* __restrict__ hb) {
    int t = blockIdx.x * 256 + threadIdx.x;     // [0, NN*32)
    if (t >= NN * 32) return;
    f32x4 v = ((const f32x4*)x)[t];
    unsigned long long pack = (unsigned long long)f2bf(v.x)
                            | ((unsigned long long)f2bf(v.y) << 16)
                            | ((unsigned long long)f2bf(v.z) << 32)
                            | ((unsigned long long)f2bf(v.w) << 48);
    ((unsigned long long*)hb)[t] = pack;
}

// ---- dense GEMM v7: r12 structure, BM=64 for occupancy; A in regs, no LDS ----
// grid = ceil(N/64) = 782; 256 thr = 4 waves (wr x wc = 2x2 over 64 rows x 128 cols/cb).
__global__ __launch_bounds__(256) void gemm_p(
        const unsigned short* __restrict__ hb,   // [N][128] bf16
        const unsigned short* __restrict__ Wt2,  // [1024][128] bf16
        unsigned short* __restrict__ P) {        // [N][1024] bf16
    int tid = threadIdx.x;
    int wid = tid >> 6, lane = tid & 63;
    int wr = wid >> 1, wc = wid & 1;
    int lm = lane & 15, lg = lane >> 4;
    int bm0 = blockIdx.x * 64;

    // A fragments: rows wr*32 + mi*16 + lm, k = ks*32 + lg*8  (each row loaded once)
    short8 af[2][4];
    #pragma unroll
    for (int mi = 0; mi < 2; ++mi) {
        int gr = bm0 + wr * 32 + mi * 16 + lm;
        #pragma unroll
        for (int ks = 0; ks < 4; ++ks) {
            short8 t = {};
            if (gr < NN) t = *(const short8*)(hb + (size_t)gr * DD + ks * 32 + lg * 8);
            af[mi][ks] = t;
        }
    }
    for (int cb = 0; cb < 8; ++cb) {
        f32x4 acc[2][4] = {};
        #pragma unroll
        for (int ks = 0; ks < 4; ++ks) {
            short8 bfr[4];
            #pragma unroll
            for (int ni = 0; ni < 4; ++ni)
                bfr[ni] = *(const short8*)(Wt2 + (size_t)(cb * 128 + wc * 64 + ni * 16 + lm) * DD
                                           + ks * 32 + lg * 8);
            #pragma unroll
            for (int mi = 0; mi < 2; ++mi)
                #pragma unroll
                for (int ni = 0; ni < 4; ++ni)
                    acc[mi][ni] = __builtin_amdgcn_mfma_f32_16x16x32_bf16(af[mi][ks], bfr[ni], acc[mi][ni], 0, 0, 0);
        }
        #pragma unroll
        for (int mi = 0; mi < 2; ++mi) {
            #pragma unroll
            for (int v = 0; v < 4; ++v) {
                int gm = bm0 + wr * 32 + mi * 16 + lg * 4 + v;
                if (gm >= NN) continue;
                #pragma unroll
                for (int ni = 0; ni < 4; ++ni) {
                    int j = cb * 128 + wc * 64 + ni * 16 + lm;
                    P[(size_t)gm * 1024 + j] = f2bf(acc[mi][ni][v]);
                }
            }
        }
    }
}

// ---- gather in P-space: wave/node, records depth-5 + hv depth-4 pipeline ----
#define PROW(r) (const unsigned*)(P + (size_t)((((r).x & 0xFFFF) << 3) | ((r).x >> 16)) * DD + lane * 2)
__global__ __launch_bounds__(256) void gather_p(
        const unsigned short* __restrict__ P,    // [N][8][128] bf16
        const int2* __restrict__ segd,
        const int2* __restrict__ edges,          // +8 zeroed slop records
        const float* __restrict__ bias,
        const float* __restrict__ hprev,         // fp32 [N][128]
        float* __restrict__ hout,
        unsigned short* __restrict__ hb_next,
        int write_next) {
    int tid = threadIdx.x;
    int wv = tid >> 6, lane = tid & 63;
    int node = blockIdx.x * 4 + wv;              // 12500*4 = 50000 exact
    int st = segd[node * RR].x;
    int2 s6 = segd[node * RR + 6];
    int end = s6.x + s6.y;

    float ax = 0.f, ay = 0.f;
    int2 r0 = edges[st];
    int2 r1 = edges[st + 1];
    int2 r2 = edges[st + 2];
    int2 r3 = edges[st + 3];
    int2 r4 = edges[st + 4];
    unsigned hv0 = *PROW(r0);
    unsigned hv1 = *PROW(r1);
    unsigned hv2 = *PROW(r2);
    unsigned hv3 = *PROW(r3);
    for (int i = st; i < end; ++i) {
        int2 r5 = edges[i + 5];
        unsigned hv4 = *PROW(r4);
        float w = __int_as_float(r0.y);
        ax += bf2f((unsigned short)(hv0 & 0xFFFF)) * w;
        ay += bf2f((unsigned short)(hv0 >> 16)) * w;
        r0 = r1; r1 = r2; r2 = r3; r3 = r4; r4 = r5;
        hv0 = hv1; hv1 = hv2; hv2 = hv3; hv3 = hv4;
    }
    unsigned hs = *(const unsigned*)(P + ((size_t)node * 8 + 7) * DD + lane * 2);
    float bx = bias[lane * 2], by = bias[lane * 2 + 1];
    f32x2 hp = ((const f32x2*)hprev)[(size_t)node * 64 + lane];
    float vx = fmaxf(ax + bf2f((unsigned short)(hs & 0xFFFF)) + bx, 0.f) + hp.x;
    float vy = fmaxf(ay + bf2f((unsigned short)(hs >> 16)) + by, 0.f) + hp.y;
    ((f32x2*)hout)[(size_t)node * 64 + lane] = (f32x2){vx, vy};
    if (write_next)
        ((unsigned*)hb_next)[(size_t)node * 64 + lane] =
            (unsigned)f2bf(vx) | ((unsigned)f2bf(vy) << 16);
}

__global__ void zero_gf(float* gf) {
    int t = blockIdx.x * 256 + threadIdx.x;
    if (t < GG * DD) gf[t] = 0.f;
}

// Parallel readout: block = 128 nodes, 8 row-streams x 32 lanes (f32x4 cols).
__global__ __launch_bounds__(256) void readout(const float* __restrict__ h,
                                               const int* __restrict__ n2g,
                                               float* __restrict__ gf) {
    int c0 = blockIdx.x * 128;
    int rg = threadIdx.x >> 5, d4 = threadIdx.x & 31;
    f32x4 acc = {0.f, 0.f, 0.f, 0.f};
    int cur = -1;
    #pragma unroll 4
    for (int it = 0; it < 16; ++it) {
        int row = c0 + it * 8 + rg;
        if (row >= NN) break;
        int g = n2g[row];
        if (g != cur) {
            if (cur >= 0) {
                atomicAdd(&gf[cur * DD + d4 * 4 + 0], acc.x);
                atomicAdd(&gf[cur * DD + d4 * 4 + 1], acc.y);
                atomicAdd(&gf[cur * DD + d4 * 4 + 2], acc.z);
                atomicAdd(&gf[cur * DD + d4 * 4 + 3], acc.w);
            }
            cur = g;
            acc = (f32x4){0.f, 0.f, 0.f, 0.f};
        }
        acc += ((const f32x4*)h)[(size_t)row * 32 + d4];
    }
    if (cur >= 0) {
        atomicAdd(&gf[cur * DD + d4 * 4 + 0], acc.x);
        atomicAdd(&gf[cur * DD + d4 * 4 + 1], acc.y);
        atomicAdd(&gf[cur * DD + d4 * 4 + 2], acc.z);
        atomicAdd(&gf[cur * DD + d4 * 4 + 3], acc.w);
    }
}

extern "C" void kernel_launch(void* const* d_in, const int* in_sizes, int n_in,
                              void* d_out, int out_size, void* d_ws, size_t ws_size,
                              hipStream_t stream) {
    const float* x      = (const float*)d_in[0];
    const int* node_in  = (const int*)d_in[1];
    const int* node_out = (const int*)d_in[2];
    const int* relation = (const int*)d_in[3];
    const float* ew     = (const float*)d_in[4];
    const int* n2g      = (const int*)d_in[5];
    const float* sl_w[3]  = {(const float*)d_in[8],  (const float*)d_in[12], (const float*)d_in[16]};
    const float* sl_b[3]  = {(const float*)d_in[9],  (const float*)d_in[13], (const float*)d_in[17]};
    const float* lin_w[3] = {(const float*)d_in[10], (const float*)d_in[14], (const float*)d_in[18]};
    const float* lin_b[3] = {(const float*)d_in[11], (const float*)d_in[15], (const float*)d_in[19]};

    float* out = (float*)d_out;
    float* gf = out;                       // [G,D]
    float* nf = out + GG * DD;             // [N,D]

    char* ws = (char*)d_ws;
    size_t off = 0;
    unsigned short* P  = (unsigned short*)(ws + off); off += (size_t)NN * 1024 * 2;   // 102.4 MB
    unsigned short* hb0 = (unsigned short*)(ws + off); off += (size_t)NN * DD * 2;    // 12.8 MB
    unsigned short* hb1 = (unsigned short*)(ws + off); off += (size_t)NN * DD * 2;    // 12.8 MB
    float* hA   = (float*)(ws + off);            off += (size_t)NN * DD * 4;          // 25.6 MB
    unsigned short* Wt2 = (unsigned short*)(ws + off); off += (size_t)3 * 1024 * DD * 2;
    float* bias = (float*)(ws + off);            off += 3 * DD * 4;
    int* counts = (int*)(ws + off);              off += (size_t)NSEG * 4;
    int* cursor = (int*)(ws + off);              off += (size_t)NSEG * 4;
    int* start  = (int*)(ws + off);              off += (size_t)NSEG * 4;
    int2* segd  = (int2*)(ws + off);             off += (size_t)NSEG * 8;
    int* bsum   = (int*)(ws + off);              off += 512 * 4;
    int2* edges = (int2*)(ws + off);             off += (size_t)(EE + 8) * 8;         // +slop

    for (int l = 0; l < 3; ++l)
        prep_w2<<<512, 256, 0, stream>>>(lin_w[l], sl_w[l], lin_b[l], sl_b[l],
                                         Wt2 + (size_t)l * 1024 * DD, bias + l * DD);

    // CSR build (layer-invariant)
    zero_ints<<<(2 * NSEG + 255) / 256, 256, 0, stream>>>(counts, 2 * NSEG);
    zero_ints<<<1, 64, 0, stream>>>((int*)(edges + EE), 16);   // zero slop records
    hist<<<(EE + 255) / 256, 256, 0, stream>>>(node_out, relation, counts);
    scan1<<<NB1, 256, 0, stream>>>(counts, start, bsum);
    scan2<<<1, 512, 0, stream>>>(bsum);
    scan3<<<(NSEG + 255) / 256, 256, 0, stream>>>(start, bsum, counts, segd);
    fill<<<(EE + 255) / 256, 256, 0, stream>>>(node_in, node_out, relation, ew,
                                               segd, cursor, edges);
    init_hb<<<(NN * 32) / 256, 256, 0, stream>>>(x, hb0);      // 6250 blocks exact

    const float* hcur = x;
    float* houts[3] = { nf, hA, nf };
    unsigned short* hbs[2] = { hb0, hb1 };
    for (int l = 0; l < 3; ++l) {
        gemm_p<<<(NN + 63) / 64, 256, 0, stream>>>(
            hbs[l & 1], Wt2 + (size_t)l * 1024 * DD, P);
        gather_p<<<NN / 4, 256, 0, stream>>>(
            P, segd, edges, bias + l * DD, hcur, houts[l],
            hbs[(l + 1) & 1], l < 2 ? 1 : 0);
        hcur = houts[l];
    }
    zero_gf<<<(GG * DD + 255) / 256, 256, 0, stream>>>(gf);
    readout<<<(NN + 127) / 128, 256, 0, stream>>>(nf, n2g, gf);
}

// Round 20
// 392.698 us; speedup vs baseline: 1.2197x; 1.2197x over previous
//
#include <hip/hip_runtime.h>
#include <hip/hip_bf16.h>

#define NN 50000
#define EE 600000
#define DD 128
#define RR 7
#define SS 8            // R + self-loop slot
#define GG 32
#define NSEG (NN * RR)  // 350000 CSR segments
#define NB1 ((NSEG + 1023) / 1024)   // 342 scan blocks

typedef float f32x4 __attribute__((ext_vector_type(4)));
typedef float f32x2 __attribute__((ext_vector_type(2)));
typedef short short8 __attribute__((ext_vector_type(8)));
typedef unsigned short u16x8 __attribute__((ext_vector_type(8)));

static __device__ __forceinline__ unsigned short f2bf(float f) {
    union { float f; unsigned u; } v; v.f = f;
    unsigned r = v.u + 0x7fff + ((v.u >> 16) & 1);
    return (unsigned short)(r >> 16);
}
static __device__ __forceinline__ float bf2f(unsigned short u) {
    union { unsigned u; float f; } v; v.u = ((unsigned)u) << 16;
    return v.f;
}

// ---- weights prep: Wt2[j=(slot,dout)][k=din] bf16; bias = lin_b + sl_b ----
__global__ void prep_w2(const float* __restrict__ lin_w, const float* __restrict__ sl_w,
                        const float* __restrict__ lin_b, const float* __restrict__ sl_b,
                        unsigned short* __restrict__ Wt2, float* __restrict__ bias) {
    int idx = blockIdx.x * 256 + threadIdx.x;   // 131072
    if (idx < DD) bias[idx] = lin_b[idx] + sl_b[idx];
    if (idx >= 1024 * DD) return;
    int j = idx >> 7;                  // output col: slot*128 + dout
    int k = idx & 127;                 // din
    int slot = j >> 7, dout = j & 127;
    float w = (slot < 7) ? lin_w[(slot * DD + k) * DD + dout] : sl_w[k * DD + dout];
    Wt2[(size_t)j * DD + k] = f2bf(w);
}

// ---- zero: counts+cursor (2*NSEG ints), slop (16 ints), gf (GG*DD floats) ----
__global__ void zero_misc(int* __restrict__ cc, int* __restrict__ slop, float* __restrict__ gf) {
    int i = blockIdx.x * 256 + threadIdx.x;
    if (i < 2 * NSEG) cc[i] = 0;
    if (i < 16) slop[i] = 0;
    if (i < GG * DD) gf[i] = 0.f;
}

__global__ void hist(const int* __restrict__ node_out, const int* __restrict__ rel,
                     int* __restrict__ counts) {
    int e = blockIdx.x * 256 + threadIdx.x;
    if (e >= EE) return;
    atomicAdd(&counts[node_out[e] * RR + rel[e]], 1);
}

__global__ __launch_bounds__(256) void scan1(const int* __restrict__ counts,
                                             int* __restrict__ start, int* __restrict__ bsum) {
    __shared__ int s[256];
    int tid = threadIdx.x;
    int base = blockIdx.x * 1024 + tid * 4;
    int v[4], sum = 0;
    #pragma unroll
    for (int j = 0; j < 4; ++j) {
        v[j] = (base + j < NSEG) ? counts[base + j] : 0;
        sum += v[j];
    }
    s[tid] = sum; __syncthreads();
    for (int off = 1; off < 256; off <<= 1) {
        int t = (tid >= off) ? s[tid - off] : 0;
        __syncthreads();
        s[tid] += t;
        __syncthreads();
    }
    int run = s[tid] - sum;
    if (tid == 255) bsum[blockIdx.x] = s[255];
    #pragma unroll
    for (int j = 0; j < 4; ++j) {
        if (base + j < NSEG) { start[base + j] = run; run += v[j]; }
    }
}

__global__ __launch_bounds__(512) void scan2(int* __restrict__ bsum) {
    __shared__ int s[512];
    int tid = threadIdx.x;
    int v = (tid < NB1) ? bsum[tid] : 0;
    s[tid] = v; __syncthreads();
    for (int off = 1; off < 512; off <<= 1) {
        int t = (tid >= off) ? s[tid - off] : 0;
        __syncthreads();
        s[tid] += t;
        __syncthreads();
    }
    if (tid < NB1) bsum[tid] = s[tid] - v;
}

__global__ void scan3(const int* __restrict__ start, const int* __restrict__ bsum,
                      const int* __restrict__ counts, int2* __restrict__ segd) {
    int i = blockIdx.x * 256 + threadIdx.x;
    if (i < NSEG) segd[i] = make_int2(start[i] + bsum[i >> 10], counts[i]);
}

// record: x = (rel << 16) | node_in, y = weight bits
__global__ void fill(const int* __restrict__ node_in, const int* __restrict__ node_out,
                     const int* __restrict__ rel, const float* __restrict__ ew,
                     const int2* __restrict__ segd, int* __restrict__ cursor,
                     int2* __restrict__ edges) {
    int e = blockIdx.x * 256 + threadIdx.x;
    if (e >= EE) return;
    int seg = node_out[e] * RR + rel[e];
    int pos = segd[seg].x + atomicAdd(&cursor[seg], 1);
    edges[pos] = make_int2((rel[e] << 16) | node_in[e], __float_as_int(ew[e]));
}

// layer-0 bf16 shadow of x.  EXACTLY NN*32 threads (6250 blocks).
__global__ void init_hb(const float* __restrict__ x, unsigned short* __restrict__ hb) {
    int t = blockIdx.x * 256 + threadIdx.x;     // [0, NN*32)
    if (t >= NN * 32) return;
    f32x4 v = ((const f32x4*)x)[t];
    unsigned long long pack = (unsigned long long)f2bf(v.x)
                            | ((unsigned long long)f2bf(v.y) << 16)
                            | ((unsigned long long)f2bf(v.z) << 32)
                            | ((unsigned long long)f2bf(v.w) << 48);
    ((unsigned long long*)hb)[t] = pack;
}

// ---- dense GEMM (r12 form, empirical best): BM=128, A in regs, direct stores ----
__global__ __launch_bounds__(256) void gemm_p(
        const unsigned short* __restrict__ hb,   // [N][128] bf16
        const unsigned short* __restrict__ Wt2,  // [1024][128] bf16
        unsigned short* __restrict__ P) {        // [N][1024] bf16
    int tid = threadIdx.x;
    int wid = tid >> 6, lane = tid & 63;
    int wr = wid >> 1, wc = wid & 1;
    int lm = lane & 15, lg = lane >> 4;
    int bm0 = blockIdx.x * 128;

    short8 af[4][4];
    #pragma unroll
    for (int mi = 0; mi < 4; ++mi) {
        int gr = bm0 + wr * 64 + mi * 16 + lm;
        #pragma unroll
        for (int ks = 0; ks < 4; ++ks) {
            short8 t = {};
            if (gr < NN) t = *(const short8*)(hb + (size_t)gr * DD + ks * 32 + lg * 8);
            af[mi][ks] = t;
        }
    }
    for (int cb = 0; cb < 8; ++cb) {
        f32x4 acc[4][4] = {};
        #pragma unroll
        for (int ks = 0; ks < 4; ++ks) {
            short8 bfr[4];
            #pragma unroll
            for (int ni = 0; ni < 4; ++ni)
                bfr[ni] = *(const short8*)(Wt2 + (size_t)(cb * 128 + wc * 64 + ni * 16 + lm) * DD
                                           + ks * 32 + lg * 8);
            #pragma unroll
            for (int mi = 0; mi < 4; ++mi)
                #pragma unroll
                for (int ni = 0; ni < 4; ++ni)
                    acc[mi][ni] = __builtin_amdgcn_mfma_f32_16x16x32_bf16(af[mi][ks], bfr[ni], acc[mi][ni], 0, 0, 0);
        }
        #pragma unroll
        for (int mi = 0; mi < 4; ++mi) {
            #pragma unroll
            for (int v = 0; v < 4; ++v) {
                int gm = bm0 + wr * 64 + mi * 16 + lg * 4 + v;
                if (gm >= NN) continue;
                #pragma unroll
                for (int ni = 0; ni < 4; ++ni) {
                    int j = cb * 128 + wc * 64 + ni * 16 + lm;
                    P[(size_t)gm * 1024 + j] = f2bf(acc[mi][ni][v]);
                }
            }
        }
    }
}

// ---- gather in P-space: wave/node, depth-5 records / depth-4 hv pipeline.
// h kept bf16: residual from hb_in; writes hb_out (l<2) or fp32 nf (last).
#define PROW(r) (const unsigned*)(P + (size_t)((((r).x & 0xFFFF) << 3) | ((r).x >> 16)) * DD + lane * 2)
__global__ __launch_bounds__(256) void gather_p(
        const unsigned short* __restrict__ P,    // [N][8][128] bf16
        const int2* __restrict__ segd,
        const int2* __restrict__ edges,          // +8 zeroed slop records
        const float* __restrict__ bias,
        const unsigned short* __restrict__ hb_in,// bf16 [N][128] (residual)
        unsigned short* __restrict__ hb_out,     // bf16 [N][128] (l<2)
        float* __restrict__ nf,                  // fp32 [N][128] (last layer)
        int last) {
    int tid = threadIdx.x;
    int wv = tid >> 6, lane = tid & 63;
    int node = blockIdx.x * 4 + wv;              // 12500*4 = 50000 exact
    int st = segd[node * RR].x;
    int2 s6 = segd[node * RR + 6];
    int end = s6.x + s6.y;

    float ax = 0.f, ay = 0.f;
    int2 r0 = edges[st];
    int2 r1 = edges[st + 1];
    int2 r2 = edges[st + 2];
    int2 r3 = edges[st + 3];
    int2 r4 = edges[st + 4];
    unsigned hv0 = *PROW(r0);
    unsigned hv1 = *PROW(r1);
    unsigned hv2 = *PROW(r2);
    unsigned hv3 = *PROW(r3);
    for (int i = st; i < end; ++i) {
        int2 r5 = edges[i + 5];
        unsigned hv4 = *PROW(r4);
        float w = __int_as_float(r0.y);
        ax += bf2f((unsigned short)(hv0 & 0xFFFF)) * w;
        ay += bf2f((unsigned short)(hv0 >> 16)) * w;
        r0 = r1; r1 = r2; r2 = r3; r3 = r4; r4 = r5;
        hv0 = hv1; hv1 = hv2; hv2 = hv3; hv3 = hv4;
    }
    unsigned hs = *(const unsigned*)(P + ((size_t)node * 8 + 7) * DD + lane * 2);
    float bx = bias[lane * 2], by = bias[lane * 2 + 1];
    unsigned hp = ((const unsigned*)hb_in)[(size_t)node * 64 + lane];
    float hpx = bf2f((unsigned short)(hp & 0xFFFF));
    float hpy = bf2f((unsigned short)(hp >> 16));
    float vx = fmaxf(ax + bf2f((unsigned short)(hs & 0xFFFF)) + bx, 0.f) + hpx;
    float vy = fmaxf(ay + bf2f((unsigned short)(hs >> 16)) + by, 0.f) + hpy;
    if (last)
        ((f32x2*)nf)[(size_t)node * 64 + lane] = (f32x2){vx, vy};
    else
        ((unsigned*)hb_out)[(size_t)node * 64 + lane] =
            (unsigned)f2bf(vx) | ((unsigned)f2bf(vy) << 16);
}

// Parallel readout: block = 128 nodes, 8 row-streams x 32 lanes (f32x4 cols).
__global__ __launch_bounds__(256) void readout(const float* __restrict__ h,
                                               const int* __restrict__ n2g,
                                               float* __restrict__ gf) {
    int c0 = blockIdx.x * 128;
    int rg = threadIdx.x >> 5, d4 = threadIdx.x & 31;
    f32x4 acc = {0.f, 0.f, 0.f, 0.f};
    int cur = -1;
    #pragma unroll 4
    for (int it = 0; it < 16; ++it) {
        int row = c0 + it * 8 + rg;
        if (row >= NN) break;
        int g = n2g[row];
        if (g != cur) {
            if (cur >= 0) {
                atomicAdd(&gf[cur * DD + d4 * 4 + 0], acc.x);
                atomicAdd(&gf[cur * DD + d4 * 4 + 1], acc.y);
                atomicAdd(&gf[cur * DD + d4 * 4 + 2], acc.z);
                atomicAdd(&gf[cur * DD + d4 * 4 + 3], acc.w);
            }
            cur = g;
            acc = (f32x4){0.f, 0.f, 0.f, 0.f};
        }
        acc += ((const f32x4*)h)[(size_t)row * 32 + d4];
    }
    if (cur >= 0) {
        atomicAdd(&gf[cur * DD + d4 * 4 + 0], acc.x);
        atomicAdd(&gf[cur * DD + d4 * 4 + 1], acc.y);
        atomicAdd(&gf[cur * DD + d4 * 4 + 2], acc.z);
        atomicAdd(&gf[cur * DD + d4 * 4 + 3], acc.w);
    }
}

extern "C" void kernel_launch(void* const* d_in, const int* in_sizes, int n_in,
                              void* d_out, int out_size, void* d_ws, size_t ws_size,
                              hipStream_t stream) {
    const float* x      = (const float*)d_in[0];
    const int* node_in  = (const int*)d_in[1];
    const int* node_out = (const int*)d_in[2];
    const int* relation = (const int*)d_in[3];
    const float* ew     = (const float*)d_in[4];
    const int* n2g      = (const int*)d_in[5];
    const float* sl_w[3]  = {(const float*)d_in[8],  (const float*)d_in[12], (const float*)d_in[16]};
    const float* sl_b[3]  = {(const float*)d_in[9],  (const float*)d_in[13], (const float*)d_in[17]};
    const float* lin_w[3] = {(const float*)d_in[10], (const float*)d_in[14], (const float*)d_in[18]};
    const float* lin_b[3] = {(const float*)d_in[11], (const float*)d_in[15], (const float*)d_in[19]};

    float* out = (float*)d_out;
    float* gf = out;                       // [G,D]
    float* nf = out + GG * DD;             // [N,D]

    char* ws = (char*)d_ws;
    size_t off = 0;
    unsigned short* P  = (unsigned short*)(ws + off); off += (size_t)NN * 1024 * 2;   // 102.4 MB
    unsigned short* hb0 = (unsigned short*)(ws + off); off += (size_t)NN * DD * 2;    // 12.8 MB
    unsigned short* hb1 = (unsigned short*)(ws + off); off += (size_t)NN * DD * 2;    // 12.8 MB
    unsigned short* Wt2 = (unsigned short*)(ws + off); off += (size_t)3 * 1024 * DD * 2;
    float* bias = (float*)(ws + off);            off += 3 * DD * 4;
    int* counts = (int*)(ws + off);              off += (size_t)NSEG * 4;
    int* cursor = (int*)(ws + off);              off += (size_t)NSEG * 4;
    int* start  = (int*)(ws + off);              off += (size_t)NSEG * 4;
    int2* segd  = (int2*)(ws + off);             off += (size_t)NSEG * 8;
    int* bsum   = (int*)(ws + off);              off += 512 * 4;
    int2* edges = (int2*)(ws + off);             off += (size_t)(EE + 8) * 8;         // +slop

    for (int l = 0; l < 3; ++l)
        prep_w2<<<512, 256, 0, stream>>>(lin_w[l], sl_w[l], lin_b[l], sl_b[l],
                                         Wt2 + (size_t)l * 1024 * DD, bias + l * DD);

    // CSR build (layer-invariant)
    zero_misc<<<(2 * NSEG + 255) / 256, 256, 0, stream>>>(counts, (int*)(edges + EE), gf);
    hist<<<(EE + 255) / 256, 256, 0, stream>>>(node_out, relation, counts);
    scan1<<<NB1, 256, 0, stream>>>(counts, start, bsum);
    scan2<<<1, 512, 0, stream>>>(bsum);
    scan3<<<(NSEG + 255) / 256, 256, 0, stream>>>(start, bsum, counts, segd);
    fill<<<(EE + 255) / 256, 256, 0, stream>>>(node_in, node_out, relation, ew,
                                               segd, cursor, edges);
    init_hb<<<(NN * 32) / 256, 256, 0, stream>>>(x, hb0);      // 6250 blocks exact

    unsigned short* hbs[2] = { hb0, hb1 };
    for (int l = 0; l < 3; ++l) {
        gemm_p<<<(NN + 127) / 128, 256, 0, stream>>>(
            hbs[l & 1], Wt2 + (size_t)l * 1024 * DD, P);
        gather_p<<<NN / 4, 256, 0, stream>>>(
            P, segd, edges, bias + l * DD, hbs[l & 1], hbs[(l + 1) & 1],
            nf, l == 2 ? 1 : 0);
    }
    readout<<<(NN + 127) / 128, 256, 0, stream>>>(nf, n2g, gf);
}

// Round 21
// 365.555 us; speedup vs baseline: 1.3103x; 1.0743x over previous
//
#include <hip/hip_runtime.h>
#include <hip/hip_bf16.h>

#define NN 50000
#define EE 600000
#define DD 128
#define RR 7
#define GG 32
#define NB1 ((NN + 1023) / 1024)   // 49 scan blocks

typedef float f32x4 __attribute__((ext_vector_type(4)));
typedef float f32x2 __attribute__((ext_vector_type(2)));
typedef short short8 __attribute__((ext_vector_type(8)));

static __device__ __forceinline__ unsigned short f2bf(float f) {
    union { float f; unsigned u; } v; v.f = f;
    unsigned r = v.u + 0x7fff + ((v.u >> 16) & 1);
    return (unsigned short)(r >> 16);
}
static __device__ __forceinline__ float bf2f(unsigned short u) {
    union { unsigned u; float f; } v; v.u = ((unsigned)u) << 16;
    return v.f;
}

// ---- weights prep, all 3 layers in one launch (12 pointer args by value) ----
__global__ void prep_w2(const float* lw0, const float* lw1, const float* lw2,
                        const float* sw0, const float* sw1, const float* sw2,
                        const float* lb0, const float* lb1, const float* lb2,
                        const float* sb0, const float* sb1, const float* sb2,
                        unsigned short* __restrict__ Wt2, float* __restrict__ bias) {
    int l = blockIdx.x >> 9;                    // 512 blocks per layer
    int idx = (blockIdx.x & 511) * 256 + threadIdx.x;
    const float* lin_w = l == 0 ? lw0 : (l == 1 ? lw1 : lw2);
    const float* sl_w  = l == 0 ? sw0 : (l == 1 ? sw1 : sw2);
    if (idx < DD) {
        const float* lin_b = l == 0 ? lb0 : (l == 1 ? lb1 : lb2);
        const float* sl_b  = l == 0 ? sb0 : (l == 1 ? sb1 : sb2);
        bias[l * DD + idx] = lin_b[idx] + sl_b[idx];
    }
    if (idx >= 1024 * DD) return;
    int j = idx >> 7;                  // output col: slot*128 + dout
    int k = idx & 127;                 // din
    int slot = j >> 7, dout = j & 127;
    float w = (slot < 7) ? lin_w[(slot * DD + k) * DD + dout] : sl_w[k * DD + dout];
    Wt2[(size_t)l * 1024 * DD + (size_t)j * DD + k] = f2bf(w);
}

// ---- zero: counts+cursor (2*NN ints), slop (16 ints), gf (GG*DD floats) ----
__global__ void zero_misc(int* __restrict__ cc, int* __restrict__ slop, float* __restrict__ gf) {
    int i = blockIdx.x * 256 + threadIdx.x;
    if (i < 2 * NN) cc[i] = 0;
    if (i < 16) slop[i] = 0;
    if (i < GG * DD) gf[i] = 0.f;
}

__global__ void hist(const int* __restrict__ node_out, int* __restrict__ counts) {
    int e = blockIdx.x * 256 + threadIdx.x;
    if (e >= EE) return;
    atomicAdd(&counts[node_out[e]], 1);
}

// exclusive scan over NN node counts: 256 thr x 4 elems per block
__global__ __launch_bounds__(256) void scan1(const int* __restrict__ counts,
                                             int* __restrict__ start, int* __restrict__ bsum) {
    __shared__ int s[256];
    int tid = threadIdx.x;
    int base = blockIdx.x * 1024 + tid * 4;
    int v[4], sum = 0;
    #pragma unroll
    for (int j = 0; j < 4; ++j) {
        v[j] = (base + j < NN) ? counts[base + j] : 0;
        sum += v[j];
    }
    s[tid] = sum; __syncthreads();
    for (int off = 1; off < 256; off <<= 1) {
        int t = (tid >= off) ? s[tid - off] : 0;
        __syncthreads();
        s[tid] += t;
        __syncthreads();
    }
    int run = s[tid] - sum;
    if (tid == 255) bsum[blockIdx.x] = s[255];
    #pragma unroll
    for (int j = 0; j < 4; ++j) {
        if (base + j < NN) { start[base + j] = run; run += v[j]; }
    }
}

__global__ __launch_bounds__(64) void scan2(int* __restrict__ bsum) {
    __shared__ int s[64];
    int tid = threadIdx.x;
    int v = (tid < NB1) ? bsum[tid] : 0;
    s[tid] = v; __syncthreads();
    for (int off = 1; off < 64; off <<= 1) {
        int t = (tid >= off) ? s[tid - off] : 0;
        __syncthreads();
        s[tid] += t;
        __syncthreads();
    }
    if (tid < NB1) bsum[tid] = s[tid] - v;
}

// segd[n] = {global start, count}
__global__ void scan3(const int* __restrict__ start, const int* __restrict__ bsum,
                      const int* __restrict__ counts, int2* __restrict__ segd) {
    int i = blockIdx.x * 256 + threadIdx.x;
    if (i < NN) segd[i] = make_int2(start[i] + bsum[i >> 10], counts[i]);
}

// record: x = (rel << 16) | node_in, y = weight bits.  Node-grouped only.
__global__ void fill(const int* __restrict__ node_in, const int* __restrict__ node_out,
                     const int* __restrict__ rel, const float* __restrict__ ew,
                     const int2* __restrict__ segd, int* __restrict__ cursor,
                     int2* __restrict__ edges) {
    int e = blockIdx.x * 256 + threadIdx.x;
    if (e >= EE) return;
    int seg = node_out[e];
    int pos = segd[seg].x + atomicAdd(&cursor[seg], 1);
    edges[pos] = make_int2((rel[e] << 16) | node_in[e], __float_as_int(ew[e]));
}

// layer-0 bf16 shadow of x.  EXACTLY NN*32 threads (6250 blocks).
__global__ void init_hb(const float* __restrict__ x, unsigned short* __restrict__ hb) {
    int t = blockIdx.x * 256 + threadIdx.x;     // [0, NN*32)
    if (t >= NN * 32) return;
    f32x4 v = ((const f32x4*)x)[t];
    unsigned long long pack = (unsigned long long)f2bf(v.x)
                            | ((unsigned long long)f2bf(v.y) << 16)
                            | ((unsigned long long)f2bf(v.z) << 32)
                            | ((unsigned long long)f2bf(v.w) << 48);
    ((unsigned long long*)hb)[t] = pack;
}

// ---- dense GEMM (r12 form, empirical best): BM=128, A in regs, direct stores ----
__global__ __launch_bounds__(256) void gemm_p(
        const unsigned short* __restrict__ hb,   // [N][128] bf16
        const unsigned short* __restrict__ Wt2,  // [1024][128] bf16
        unsigned short* __restrict__ P) {        // [N][1024] bf16
    int tid = threadIdx.x;
    int wid = tid >> 6, lane = tid & 63;
    int wr = wid >> 1, wc = wid & 1;
    int lm = lane & 15, lg = lane >> 4;
    int bm0 = blockIdx.x * 128;

    short8 af[4][4];
    #pragma unroll
    for (int mi = 0; mi < 4; ++mi) {
        int gr = bm0 + wr * 64 + mi * 16 + lm;
        #pragma unroll
        for (int ks = 0; ks < 4; ++ks) {
            short8 t = {};
            if (gr < NN) t = *(const short8*)(hb + (size_t)gr * DD + ks * 32 + lg * 8);
            af[mi][ks] = t;
        }
    }
    for (int cb = 0; cb < 8; ++cb) {
        f32x4 acc[4][4] = {};
        #pragma unroll
        for (int ks = 0; ks < 4; ++ks) {
            short8 bfr[4];
            #pragma unroll
            for (int ni = 0; ni < 4; ++ni)
                bfr[ni] = *(const short8*)(Wt2 + (size_t)(cb * 128 + wc * 64 + ni * 16 + lm) * DD
                                           + ks * 32 + lg * 8);
            #pragma unroll
            for (int mi = 0; mi < 4; ++mi)
                #pragma unroll
                for (int ni = 0; ni < 4; ++ni)
                    acc[mi][ni] = __builtin_amdgcn_mfma_f32_16x16x32_bf16(af[mi][ks], bfr[ni], acc[mi][ni], 0, 0, 0);
        }
        #pragma unroll
        for (int mi = 0; mi < 4; ++mi) {
            #pragma unroll
            for (int v = 0; v < 4; ++v) {
                int gm = bm0 + wr * 64 + mi * 16 + lg * 4 + v;
                if (gm >= NN) continue;
                #pragma unroll
                for (int ni = 0; ni < 4; ++ni) {
                    int j = cb * 128 + wc * 64 + ni * 16 + lm;
                    P[(size_t)gm * 1024 + j] = f2bf(acc[mi][ni][v]);
                }
            }
        }
    }
}

// ---- gather: wave/node, half-wave per edge stream (even/odd), depth-3/half ----
// lane = h*32 + l5; half h walks edges h, h+2, ...; lane covers cols l5*4..l5*4+3.
#define PR(r) ((const uint2*)(P + (size_t)(((((r).x & 0xFFFF) << 3) | ((r).x >> 16))) * DD) + l5)
__global__ __launch_bounds__(256) void gather_p(
        const unsigned short* __restrict__ P,    // [N][8][128] bf16
        const int2* __restrict__ segd,           // [N] {start,count}
        const int2* __restrict__ edges,          // +8 zeroed slop records
        const float* __restrict__ bias,
        const unsigned short* __restrict__ hb_in,// bf16 [N][128] (residual)
        unsigned short* __restrict__ hb_out,     // bf16 [N][128] (l<2)
        float* __restrict__ nf,                  // fp32 [N][128] (last layer)
        int last) {
    int tid = threadIdx.x;
    int wv = tid >> 6, lane = tid & 63;
    int h = lane >> 5, l5 = lane & 31;
    int node = blockIdx.x * 4 + wv;              // 12500*4 = 50000 exact
    int2 sd = segd[node];
    int st = sd.x, cnt = sd.y;
    int base = st + h;
    int mmax = (cnt + 1) >> 1;

    f32x4 ac = {0.f, 0.f, 0.f, 0.f};
    int2 r0 = edges[base];
    int2 r1 = edges[base + 2];
    int2 r2 = edges[base + 4];
    uint2 hv0 = *PR(r0);
    uint2 hv1 = *PR(r1);
    for (int i = 0; i < mmax; ++i) {
        int2 r3 = edges[base + 2 * i + 6];
        uint2 hv2 = *PR(r2);
        if (h + 2 * i < cnt) {
            float w = __int_as_float(r0.y);
            ac.x += bf2f((unsigned short)(hv0.x & 0xFFFF)) * w;
            ac.y += bf2f((unsigned short)(hv0.x >> 16)) * w;
            ac.z += bf2f((unsigned short)(hv0.y & 0xFFFF)) * w;
            ac.w += bf2f((unsigned short)(hv0.y >> 16)) * w;
        }
        r0 = r1; r1 = r2; r2 = r3;
        hv0 = hv1; hv1 = hv2;
    }
    // combine halves: even-edge sums + odd-edge sums
    ac.x += __shfl_xor(ac.x, 32);
    ac.y += __shfl_xor(ac.y, 32);
    ac.z += __shfl_xor(ac.z, 32);
    ac.w += __shfl_xor(ac.w, 32);

    if (h == 0) {
        uint2 hs = *((const uint2*)(P + ((size_t)node * 8 + 7) * DD) + l5);
        f32x4 b4 = ((const f32x4*)bias)[l5];
        uint2 hp = ((const uint2*)hb_in)[(size_t)node * 32 + l5];
        float o0 = fmaxf(ac.x + bf2f((unsigned short)(hs.x & 0xFFFF)) + b4.x, 0.f) + bf2f((unsigned short)(hp.x & 0xFFFF));
        float o1 = fmaxf(ac.y + bf2f((unsigned short)(hs.x >> 16))   + b4.y, 0.f) + bf2f((unsigned short)(hp.x >> 16));
        float o2 = fmaxf(ac.z + bf2f((unsigned short)(hs.y & 0xFFFF)) + b4.z, 0.f) + bf2f((unsigned short)(hp.y & 0xFFFF));
        float o3 = fmaxf(ac.w + bf2f((unsigned short)(hs.y >> 16))   + b4.w, 0.f) + bf2f((unsigned short)(hp.y >> 16));
        if (last) {
            ((f32x4*)nf)[(size_t)node * 32 + l5] = (f32x4){o0, o1, o2, o3};
        } else {
            uint2 pk;
            pk.x = (unsigned)f2bf(o0) | ((unsigned)f2bf(o1) << 16);
            pk.y = (unsigned)f2bf(o2) | ((unsigned)f2bf(o3) << 16);
            ((uint2*)hb_out)[(size_t)node * 32 + l5] = pk;
        }
    }
}

// Parallel readout: block = 128 nodes, 8 row-streams x 32 lanes (f32x4 cols).
__global__ __launch_bounds__(256) void readout(const float* __restrict__ h,
                                               const int* __restrict__ n2g,
                                               float* __restrict__ gf) {
    int c0 = blockIdx.x * 128;
    int rg = threadIdx.x >> 5, d4 = threadIdx.x & 31;
    f32x4 acc = {0.f, 0.f, 0.f, 0.f};
    int cur = -1;
    #pragma unroll 4
    for (int it = 0; it < 16; ++it) {
        int row = c0 + it * 8 + rg;
        if (row >= NN) break;
        int g = n2g[row];
        if (g != cur) {
            if (cur >= 0) {
                atomicAdd(&gf[cur * DD + d4 * 4 + 0], acc.x);
                atomicAdd(&gf[cur * DD + d4 * 4 + 1], acc.y);
                atomicAdd(&gf[cur * DD + d4 * 4 + 2], acc.z);
                atomicAdd(&gf[cur * DD + d4 * 4 + 3], acc.w);
            }
            cur = g;
            acc = (f32x4){0.f, 0.f, 0.f, 0.f};
        }
        acc += ((const f32x4*)h)[(size_t)row * 32 + d4];
    }
    if (cur >= 0) {
        atomicAdd(&gf[cur * DD + d4 * 4 + 0], acc.x);
        atomicAdd(&gf[cur * DD + d4 * 4 + 1], acc.y);
        atomicAdd(&gf[cur * DD + d4 * 4 + 2], acc.z);
        atomicAdd(&gf[cur * DD + d4 * 4 + 3], acc.w);
    }
}

extern "C" void kernel_launch(void* const* d_in, const int* in_sizes, int n_in,
                              void* d_out, int out_size, void* d_ws, size_t ws_size,
                              hipStream_t stream) {
    const float* x      = (const float*)d_in[0];
    const int* node_in  = (const int*)d_in[1];
    const int* node_out = (const int*)d_in[2];
    const int* relation = (const int*)d_in[3];
    const float* ew     = (const float*)d_in[4];
    const int* n2g      = (const int*)d_in[5];

    float* out = (float*)d_out;
    float* gf = out;                       // [G,D]
    float* nf = out + GG * DD;             // [N,D]

    char* ws = (char*)d_ws;
    size_t off = 0;
    unsigned short* P  = (unsigned short*)(ws + off); off += (size_t)NN * 1024 * 2;   // 102.4 MB
    unsigned short* hb0 = (unsigned short*)(ws + off); off += (size_t)NN * DD * 2;    // 12.8 MB
    unsigned short* hb1 = (unsigned short*)(ws + off); off += (size_t)NN * DD * 2;    // 12.8 MB
    unsigned short* Wt2 = (unsigned short*)(ws + off); off += (size_t)3 * 1024 * DD * 2;
    float* bias = (float*)(ws + off);            off += 3 * DD * 4;
    int* counts = (int*)(ws + off);              off += (size_t)NN * 4;
    int* cursor = (int*)(ws + off);              off += (size_t)NN * 4;
    int* start  = (int*)(ws + off);              off += (size_t)NN * 4;
    int2* segd  = (int2*)(ws + off);             off += (size_t)NN * 8;
    int* bsum   = (int*)(ws + off);              off += 64 * 4;
    int2* edges = (int2*)(ws + off);             off += (size_t)(EE + 8) * 8;         // +slop

    prep_w2<<<3 * 512, 256, 0, stream>>>(
        (const float*)d_in[10], (const float*)d_in[14], (const float*)d_in[18],
        (const float*)d_in[8],  (const float*)d_in[12], (const float*)d_in[16],
        (const float*)d_in[11], (const float*)d_in[15], (const float*)d_in[19],
        (const float*)d_in[9],  (const float*)d_in[13], (const float*)d_in[17],
        Wt2, bias);

    // CSR build (node-grouped; layer-invariant)
    zero_misc<<<(2 * NN + 255) / 256, 256, 0, stream>>>(counts, (int*)(edges + EE), gf);
    hist<<<(EE + 255) / 256, 256, 0, stream>>>(node_out, counts);
    scan1<<<NB1, 256, 0, stream>>>(counts, start, bsum);
    scan2<<<1, 64, 0, stream>>>(bsum);
    scan3<<<(NN + 255) / 256, 256, 0, stream>>>(start, bsum, counts, segd);
    fill<<<(EE + 255) / 256, 256, 0, stream>>>(node_in, node_out, relation, ew,
                                               segd, cursor, edges);
    init_hb<<<(NN * 32) / 256, 256, 0, stream>>>(x, hb0);      // 6250 blocks exact

    unsigned short* hbs[2] = { hb0, hb1 };
    for (int l = 0; l < 3; ++l) {
        gemm_p<<<(NN + 127) / 128, 256, 0, stream>>>(
            hbs[l & 1], Wt2 + (size_t)l * 1024 * DD, P);
        gather_p<<<NN / 4, 256, 0, stream>>>(
            P, segd, edges, bias + l * DD, hbs[l & 1], hbs[(l + 1) & 1],
            nf, l == 2 ? 1 : 0);
    }
    readout<<<(NN + 127) / 128, 256, 0, stream>>>(nf, n2g, gf);
}

// Round 22
// 363.069 us; speedup vs baseline: 1.3192x; 1.0068x over previous
//
#include <hip/hip_runtime.h>
#include <hip/hip_bf16.h>

#define NN 50000
#define EE 600000
#define DD 128
#define RR 7
#define GG 32
#define NB1 ((NN + 1023) / 1024)   // 49 scan blocks

typedef float f32x4 __attribute__((ext_vector_type(4)));
typedef float f32x2 __attribute__((ext_vector_type(2)));
typedef short short8 __attribute__((ext_vector_type(8)));

static __device__ __forceinline__ unsigned short f2bf(float f) {
    union { float f; unsigned u; } v; v.f = f;
    unsigned r = v.u + 0x7fff + ((v.u >> 16) & 1);
    return (unsigned short)(r >> 16);
}
static __device__ __forceinline__ float bf2f(unsigned short u) {
    union { unsigned u; float f; } v; v.u = ((unsigned)u) << 16;
    return v.f;
}

// ---- weights prep, all 3 layers in one launch (12 pointer args by value) ----
__global__ void prep_w2(const float* lw0, const float* lw1, const float* lw2,
                        const float* sw0, const float* sw1, const float* sw2,
                        const float* lb0, const float* lb1, const float* lb2,
                        const float* sb0, const float* sb1, const float* sb2,
                        unsigned short* __restrict__ Wt2, float* __restrict__ bias) {
    int l = blockIdx.x >> 9;                    // 512 blocks per layer
    int idx = (blockIdx.x & 511) * 256 + threadIdx.x;
    const float* lin_w = l == 0 ? lw0 : (l == 1 ? lw1 : lw2);
    const float* sl_w  = l == 0 ? sw0 : (l == 1 ? sw1 : sw2);
    if (idx < DD) {
        const float* lin_b = l == 0 ? lb0 : (l == 1 ? lb1 : lb2);
        const float* sl_b  = l == 0 ? sb0 : (l == 1 ? sb1 : sb2);
        bias[l * DD + idx] = lin_b[idx] + sl_b[idx];
    }
    if (idx >= 1024 * DD) return;
    int j = idx >> 7;                  // output col: slot*128 + dout
    int k = idx & 127;                 // din
    int slot = j >> 7, dout = j & 127;
    float w = (slot < 7) ? lin_w[(slot * DD + k) * DD + dout] : sl_w[k * DD + dout];
    Wt2[(size_t)l * 1024 * DD + (size_t)j * DD + k] = f2bf(w);
}

// ---- zero: counts+cursor (2*NN ints), slop (16 ints), gf (GG*DD floats) ----
__global__ void zero_misc(int* __restrict__ cc, int* __restrict__ slop, float* __restrict__ gf) {
    int i = blockIdx.x * 256 + threadIdx.x;
    if (i < 2 * NN) cc[i] = 0;
    if (i < 16) slop[i] = 0;
    if (i < GG * DD) gf[i] = 0.f;
}

__global__ void hist(const int* __restrict__ node_out, int* __restrict__ counts) {
    int e = blockIdx.x * 256 + threadIdx.x;
    if (e >= EE) return;
    atomicAdd(&counts[node_out[e]], 1);
}

// exclusive scan over NN node counts: 256 thr x 4 elems per block
__global__ __launch_bounds__(256) void scan1(const int* __restrict__ counts,
                                             int* __restrict__ start, int* __restrict__ bsum) {
    __shared__ int s[256];
    int tid = threadIdx.x;
    int base = blockIdx.x * 1024 + tid * 4;
    int v[4], sum = 0;
    #pragma unroll
    for (int j = 0; j < 4; ++j) {
        v[j] = (base + j < NN) ? counts[base + j] : 0;
        sum += v[j];
    }
    s[tid] = sum; __syncthreads();
    for (int off = 1; off < 256; off <<= 1) {
        int t = (tid >= off) ? s[tid - off] : 0;
        __syncthreads();
        s[tid] += t;
        __syncthreads();
    }
    int run = s[tid] - sum;
    if (tid == 255) bsum[blockIdx.x] = s[255];
    #pragma unroll
    for (int j = 0; j < 4; ++j) {
        if (base + j < NN) { start[base + j] = run; run += v[j]; }
    }
}

__global__ __launch_bounds__(64) void scan2(int* __restrict__ bsum) {
    __shared__ int s[64];
    int tid = threadIdx.x;
    int v = (tid < NB1) ? bsum[tid] : 0;
    s[tid] = v; __syncthreads();
    for (int off = 1; off < 64; off <<= 1) {
        int t = (tid >= off) ? s[tid - off] : 0;
        __syncthreads();
        s[tid] += t;
        __syncthreads();
    }
    if (tid < NB1) bsum[tid] = s[tid] - v;
}

// segd[n] = {global start, count}
__global__ void scan3(const int* __restrict__ start, const int* __restrict__ bsum,
                      const int* __restrict__ counts, int2* __restrict__ segd) {
    int i = blockIdx.x * 256 + threadIdx.x;
    if (i < NN) segd[i] = make_int2(start[i] + bsum[i >> 10], counts[i]);
}

// record: x = (rel << 16) | node_in, y = weight bits.  Node-grouped only.
__global__ void fill(const int* __restrict__ node_in, const int* __restrict__ node_out,
                     const int* __restrict__ rel, const float* __restrict__ ew,
                     const int2* __restrict__ segd, int* __restrict__ cursor,
                     int2* __restrict__ edges) {
    int e = blockIdx.x * 256 + threadIdx.x;
    if (e >= EE) return;
    int seg = node_out[e];
    int pos = segd[seg].x + atomicAdd(&cursor[seg], 1);
    edges[pos] = make_int2((rel[e] << 16) | node_in[e], __float_as_int(ew[e]));
}

// layer-0 bf16 shadow of x.  EXACTLY NN*32 threads (6250 blocks).
__global__ void init_hb(const float* __restrict__ x, unsigned short* __restrict__ hb) {
    int t = blockIdx.x * 256 + threadIdx.x;     // [0, NN*32)
    if (t >= NN * 32) return;
    f32x4 v = ((const f32x4*)x)[t];
    unsigned long long pack = (unsigned long long)f2bf(v.x)
                            | ((unsigned long long)f2bf(v.y) << 16)
                            | ((unsigned long long)f2bf(v.z) << 32)
                            | ((unsigned long long)f2bf(v.w) << 48);
    ((unsigned long long*)hb)[t] = pack;
}

// ---- dense GEMM (r12 form, empirical best): BM=128, A in regs, direct stores ----
__global__ __launch_bounds__(256) void gemm_p(
        const unsigned short* __restrict__ hb,   // [N][128] bf16
        const unsigned short* __restrict__ Wt2,  // [1024][128] bf16
        unsigned short* __restrict__ P) {        // [N][1024] bf16
    int tid = threadIdx.x;
    int wid = tid >> 6, lane = tid & 63;
    int wr = wid >> 1, wc = wid & 1;
    int lm = lane & 15, lg = lane >> 4;
    int bm0 = blockIdx.x * 128;

    short8 af[4][4];
    #pragma unroll
    for (int mi = 0; mi < 4; ++mi) {
        int gr = bm0 + wr * 64 + mi * 16 + lm;
        #pragma unroll
        for (int ks = 0; ks < 4; ++ks) {
            short8 t = {};
            if (gr < NN) t = *(const short8*)(hb + (size_t)gr * DD + ks * 32 + lg * 8);
            af[mi][ks] = t;
        }
    }
    for (int cb = 0; cb < 8; ++cb) {
        f32x4 acc[4][4] = {};
        #pragma unroll
        for (int ks = 0; ks < 4; ++ks) {
            short8 bfr[4];
            #pragma unroll
            for (int ni = 0; ni < 4; ++ni)
                bfr[ni] = *(const short8*)(Wt2 + (size_t)(cb * 128 + wc * 64 + ni * 16 + lm) * DD
                                           + ks * 32 + lg * 8);
            #pragma unroll
            for (int mi = 0; mi < 4; ++mi)
                #pragma unroll
                for (int ni = 0; ni < 4; ++ni)
                    acc[mi][ni] = __builtin_amdgcn_mfma_f32_16x16x32_bf16(af[mi][ks], bfr[ni], acc[mi][ni], 0, 0, 0);
        }
        #pragma unroll
        for (int mi = 0; mi < 4; ++mi) {
            #pragma unroll
            for (int v = 0; v < 4; ++v) {
                int gm = bm0 + wr * 64 + mi * 16 + lg * 4 + v;
                if (gm >= NN) continue;
                #pragma unroll
                for (int ni = 0; ni < 4; ++ni) {
                    int j = cb * 128 + wc * 64 + ni * 16 + lm;
                    P[(size_t)gm * 1024 + j] = f2bf(acc[mi][ni][v]);
                }
            }
        }
    }
}

// ---- gather: wave/node, half-wave per edge stream (even/odd), depth-3/half ----
// lane = h*32 + l5; half h walks edges h, h+2, ...; lane covers cols l5*4..l5*4+3.
#define PR(r) ((const uint2*)(P + (size_t)(((((r).x & 0xFFFF) << 3) | ((r).x >> 16))) * DD) + l5)
__global__ __launch_bounds__(256) void gather_p(
        const unsigned short* __restrict__ P,    // [N][8][128] bf16
        const int2* __restrict__ segd,           // [N] {start,count}
        const int2* __restrict__ edges,          // +8 zeroed slop records
        const float* __restrict__ bias,
        const unsigned short* __restrict__ hb_in,// bf16 [N][128] (residual)
        unsigned short* __restrict__ hb_out,     // bf16 [N][128] (l<2)
        float* __restrict__ nf,                  // fp32 [N][128] (last layer)
        int last) {
    int tid = threadIdx.x;
    int wv = tid >> 6, lane = tid & 63;
    int h = lane >> 5, l5 = lane & 31;
    int node = blockIdx.x * 4 + wv;              // 12500*4 = 50000 exact
    int2 sd = segd[node];
    int st = sd.x, cnt = sd.y;
    int base = st + h;
    int mmax = (cnt + 1) >> 1;

    f32x4 ac = {0.f, 0.f, 0.f, 0.f};
    int2 r0 = edges[base];
    int2 r1 = edges[base + 2];
    int2 r2 = edges[base + 4];
    uint2 hv0 = *PR(r0);
    uint2 hv1 = *PR(r1);
    for (int i = 0; i < mmax; ++i) {
        int2 r3 = edges[base + 2 * i + 6];
        uint2 hv2 = *PR(r2);
        if (h + 2 * i < cnt) {
            float w = __int_as_float(r0.y);
            ac.x += bf2f((unsigned short)(hv0.x & 0xFFFF)) * w;
            ac.y += bf2f((unsigned short)(hv0.x >> 16)) * w;
            ac.z += bf2f((unsigned short)(hv0.y & 0xFFFF)) * w;
            ac.w += bf2f((unsigned short)(hv0.y >> 16)) * w;
        }
        r0 = r1; r1 = r2; r2 = r3;
        hv0 = hv1; hv1 = hv2;
    }
    // combine halves: even-edge sums + odd-edge sums
    ac.x += __shfl_xor(ac.x, 32);
    ac.y += __shfl_xor(ac.y, 32);
    ac.z += __shfl_xor(ac.z, 32);
    ac.w += __shfl_xor(ac.w, 32);

    if (h == 0) {
        uint2 hs = *((const uint2*)(P + ((size_t)node * 8 + 7) * DD) + l5);
        f32x4 b4 = ((const f32x4*)bias)[l5];
        uint2 hp = ((const uint2*)hb_in)[(size_t)node * 32 + l5];
        float o0 = fmaxf(ac.x + bf2f((unsigned short)(hs.x & 0xFFFF)) + b4.x, 0.f) + bf2f((unsigned short)(hp.x & 0xFFFF));
        float o1 = fmaxf(ac.y + bf2f((unsigned short)(hs.x >> 16))   + b4.y, 0.f) + bf2f((unsigned short)(hp.x >> 16));
        float o2 = fmaxf(ac.z + bf2f((unsigned short)(hs.y & 0xFFFF)) + b4.z, 0.f) + bf2f((unsigned short)(hp.y & 0xFFFF));
        float o3 = fmaxf(ac.w + bf2f((unsigned short)(hs.y >> 16))   + b4.w, 0.f) + bf2f((unsigned short)(hp.y >> 16));
        if (last) {
            ((f32x4*)nf)[(size_t)node * 32 + l5] = (f32x4){o0, o1, o2, o3};
        } else {
            uint2 pk;
            pk.x = (unsigned)f2bf(o0) | ((unsigned)f2bf(o1) << 16);
            pk.y = (unsigned)f2bf(o2) | ((unsigned)f2bf(o3) << 16);
            ((uint2*)hb_out)[(size_t)node * 32 + l5] = pk;
        }
    }
}

// Parallel readout: block = 128 nodes, 8 row-streams x 32 lanes (f32x4 cols).
__global__ __launch_bounds__(256) void readout(const float* __restrict__ h,
                                               const int* __restrict__ n2g,
                                               float* __restrict__ gf) {
    int c0 = blockIdx.x * 128;
    int rg = threadIdx.x >> 5, d4 = threadIdx.x & 31;
    f32x4 acc = {0.f, 0.f, 0.f, 0.f};
    int cur = -1;
    #pragma unroll 4
    for (int it = 0; it < 16; ++it) {
        int row = c0 + it * 8 + rg;
        if (row >= NN) break;
        int g = n2g[row];
        if (g != cur) {
            if (cur >= 0) {
                atomicAdd(&gf[cur * DD + d4 * 4 + 0], acc.x);
                atomicAdd(&gf[cur * DD + d4 * 4 + 1], acc.y);
                atomicAdd(&gf[cur * DD + d4 * 4 + 2], acc.z);
                atomicAdd(&gf[cur * DD + d4 * 4 + 3], acc.w);
            }
            cur = g;
            acc = (f32x4){0.f, 0.f, 0.f, 0.f};
        }
        acc += ((const f32x4*)h)[(size_t)row * 32 + d4];
    }
    if (cur >= 0) {
        atomicAdd(&gf[cur * DD + d4 * 4 + 0], acc.x);
        atomicAdd(&gf[cur * DD + d4 * 4 + 1], acc.y);
        atomicAdd(&gf[cur * DD + d4 * 4 + 2], acc.z);
        atomicAdd(&gf[cur * DD + d4 * 4 + 3], acc.w);
    }
}

extern "C" void kernel_launch(void* const* d_in, const int* in_sizes, int n_in,
                              void* d_out, int out_size, void* d_ws, size_t ws_size,
                              hipStream_t stream) {
    const float* x      = (const float*)d_in[0];
    const int* node_in  = (const int*)d_in[1];
    const int* node_out = (const int*)d_in[2];
    const int* relation = (const int*)d_in[3];
    const float* ew     = (const float*)d_in[4];
    const int* n2g      = (const int*)d_in[5];

    float* out = (float*)d_out;
    float* gf = out;                       // [G,D]
    float* nf = out + GG * DD;             // [N,D]

    char* ws = (char*)d_ws;
    size_t off = 0;
    unsigned short* P  = (unsigned short*)(ws + off); off += (size_t)NN * 1024 * 2;   // 102.4 MB
    unsigned short* hb0 = (unsigned short*)(ws + off); off += (size_t)NN * DD * 2;    // 12.8 MB
    unsigned short* hb1 = (unsigned short*)(ws + off); off += (size_t)NN * DD * 2;    // 12.8 MB
    unsigned short* Wt2 = (unsigned short*)(ws + off); off += (size_t)3 * 1024 * DD * 2;
    float* bias = (float*)(ws + off);            off += 3 * DD * 4;
    int* counts = (int*)(ws + off);              off += (size_t)NN * 4;
    int* cursor = (int*)(ws + off);              off += (size_t)NN * 4;
    int* start  = (int*)(ws + off);              off += (size_t)NN * 4;
    int2* segd  = (int2*)(ws + off);             off += (size_t)NN * 8;
    int* bsum   = (int*)(ws + off);              off += 64 * 4;
    int2* edges = (int2*)(ws + off);             off += (size_t)(EE + 8) * 8;         // +slop

    prep_w2<<<3 * 512, 256, 0, stream>>>(
        (const float*)d_in[10], (const float*)d_in[14], (const float*)d_in[18],
        (const float*)d_in[8],  (const float*)d_in[12], (const float*)d_in[16],
        (const float*)d_in[11], (const float*)d_in[15], (const float*)d_in[19],
        (const float*)d_in[9],  (const float*)d_in[13], (const float*)d_in[17],
        Wt2, bias);

    // CSR build (node-grouped; layer-invariant)
    zero_misc<<<(2 * NN + 255) / 256, 256, 0, stream>>>(counts, (int*)(edges + EE), gf);
    hist<<<(EE + 255) / 256, 256, 0, stream>>>(node_out, counts);
    scan1<<<NB1, 256, 0, stream>>>(counts, start, bsum);
    scan2<<<1, 64, 0, stream>>>(bsum);
    scan3<<<(NN + 255) / 256, 256, 0, stream>>>(start, bsum, counts, segd);
    fill<<<(EE + 255) / 256, 256, 0, stream>>>(node_in, node_out, relation, ew,
                                               segd, cursor, edges);
    init_hb<<<(NN * 32) / 256, 256, 0, stream>>>(x, hb0);      // 6250 blocks exact

    unsigned short* hbs[2] = { hb0, hb1 };
    for (int l = 0; l < 3; ++l) {
        gemm_p<<<(NN + 127) / 128, 256, 0, stream>>>(
            hbs[l & 1], Wt2 + (size_t)l * 1024 * DD, P);
        gather_p<<<NN / 4, 256, 0, stream>>>(
            P, segd, edges, bias + l * DD, hbs[l & 1], hbs[(l + 1) & 1],
            nf, l == 2 ? 1 : 0);
    }
    readout<<<(NN + 127) / 128, 256, 0, stream>>>(nf, n2g, gf);
}

// Round 23
// 358.889 us; speedup vs baseline: 1.3346x; 1.0116x over previous
//
#include <hip/hip_runtime.h>
#include <hip/hip_bf16.h>

#define NN 50000
#define EE 600000
#define DD 128
#define RR 7
#define GG 32
#define NB1 ((NN + 1023) / 1024)   // 49 scan blocks

typedef float f32x4 __attribute__((ext_vector_type(4)));
typedef short short8 __attribute__((ext_vector_type(8)));
typedef unsigned u32x4 __attribute__((ext_vector_type(4)));

static __device__ __forceinline__ unsigned short f2bf(float f) {
    union { float f; unsigned u; } v; v.f = f;
    unsigned r = v.u + 0x7fff + ((v.u >> 16) & 1);
    return (unsigned short)(r >> 16);
}
static __device__ __forceinline__ float bf2f(unsigned short u) {
    union { unsigned u; float f; } v; v.u = ((unsigned)u) << 16;
    return v.f;
}

// ---- weights prep, all 3 layers in one launch ----
__global__ void prep_w2(const float* lw0, const float* lw1, const float* lw2,
                        const float* sw0, const float* sw1, const float* sw2,
                        const float* lb0, const float* lb1, const float* lb2,
                        const float* sb0, const float* sb1, const float* sb2,
                        unsigned short* __restrict__ Wt2, float* __restrict__ bias) {
    int l = blockIdx.x >> 9;                    // 512 blocks per layer
    int idx = (blockIdx.x & 511) * 256 + threadIdx.x;
    const float* lin_w = l == 0 ? lw0 : (l == 1 ? lw1 : lw2);
    const float* sl_w  = l == 0 ? sw0 : (l == 1 ? sw1 : sw2);
    if (idx < DD) {
        const float* lin_b = l == 0 ? lb0 : (l == 1 ? lb1 : lb2);
        const float* sl_b  = l == 0 ? sb0 : (l == 1 ? sb1 : sb2);
        bias[l * DD + idx] = lin_b[idx] + sl_b[idx];
    }
    if (idx >= 1024 * DD) return;
    int j = idx >> 7;                  // output col: slot*128 + dout
    int k = idx & 127;                 // din
    int slot = j >> 7, dout = j & 127;
    float w = (slot < 7) ? lin_w[(slot * DD + k) * DD + dout] : sl_w[k * DD + dout];
    Wt2[(size_t)l * 1024 * DD + (size_t)j * DD + k] = f2bf(w);
}

// ---- zero: counts+cursor (2*NN ints), slop (32 ints), gf (GG*DD floats) ----
__global__ void zero_misc(int* __restrict__ cc, int* __restrict__ slop, float* __restrict__ gf) {
    int i = blockIdx.x * 256 + threadIdx.x;
    if (i < 2 * NN) cc[i] = 0;
    if (i < 32) slop[i] = 0;
    if (i < GG * DD) gf[i] = 0.f;
}

__global__ void hist(const int* __restrict__ node_out, int* __restrict__ counts) {
    int e = blockIdx.x * 256 + threadIdx.x;
    if (e >= EE) return;
    atomicAdd(&counts[node_out[e]], 1);
}

__global__ __launch_bounds__(256) void scan1(const int* __restrict__ counts,
                                             int* __restrict__ start, int* __restrict__ bsum) {
    __shared__ int s[256];
    int tid = threadIdx.x;
    int base = blockIdx.x * 1024 + tid * 4;
    int v[4], sum = 0;
    #pragma unroll
    for (int j = 0; j < 4; ++j) {
        v[j] = (base + j < NN) ? counts[base + j] : 0;
        sum += v[j];
    }
    s[tid] = sum; __syncthreads();
    for (int off = 1; off < 256; off <<= 1) {
        int t = (tid >= off) ? s[tid - off] : 0;
        __syncthreads();
        s[tid] += t;
        __syncthreads();
    }
    int run = s[tid] - sum;
    if (tid == 255) bsum[blockIdx.x] = s[255];
    #pragma unroll
    for (int j = 0; j < 4; ++j) {
        if (base + j < NN) { start[base + j] = run; run += v[j]; }
    }
}

__global__ __launch_bounds__(64) void scan2(int* __restrict__ bsum) {
    __shared__ int s[64];
    int tid = threadIdx.x;
    int v = (tid < NB1) ? bsum[tid] : 0;
    s[tid] = v; __syncthreads();
    for (int off = 1; off < 64; off <<= 1) {
        int t = (tid >= off) ? s[tid - off] : 0;
        __syncthreads();
        s[tid] += t;
        __syncthreads();
    }
    if (tid < NB1) bsum[tid] = s[tid] - v;
}

__global__ void scan3(const int* __restrict__ start, const int* __restrict__ bsum,
                      const int* __restrict__ counts, int2* __restrict__ segd) {
    int i = blockIdx.x * 256 + threadIdx.x;
    if (i < NN) segd[i] = make_int2(start[i] + bsum[i >> 10], counts[i]);
}

// record: x = (rel << 16) | node_in, y = weight bits.  Node-grouped.
__global__ void fill(const int* __restrict__ node_in, const int* __restrict__ node_out,
                     const int* __restrict__ rel, const float* __restrict__ ew,
                     const int2* __restrict__ segd, int* __restrict__ cursor,
                     int2* __restrict__ edges) {
    int e = blockIdx.x * 256 + threadIdx.x;
    if (e >= EE) return;
    int seg = node_out[e];
    int pos = segd[seg].x + atomicAdd(&cursor[seg], 1);
    edges[pos] = make_int2((rel[e] << 16) | node_in[e], __float_as_int(ew[e]));
}

// ---- dense GEMM (r12 form): BM=128, A in regs, direct stores.
// Layer 0 reads fp32 x directly (xf != nullptr); else bf16 hb.
__global__ __launch_bounds__(256) void gemm_p(
        const unsigned short* __restrict__ hb,   // [N][128] bf16 (l>0)
        const float* __restrict__ xf,            // [N][128] fp32 (l==0) or null
        const unsigned short* __restrict__ Wt2,  // [1024][128] bf16
        unsigned short* __restrict__ P) {        // [N][1024] bf16
    int tid = threadIdx.x;
    int wid = tid >> 6, lane = tid & 63;
    int wr = wid >> 1, wc = wid & 1;
    int lm = lane & 15, lg = lane >> 4;
    int bm0 = blockIdx.x * 128;

    short8 af[4][4];
    if (xf) {
        #pragma unroll
        for (int mi = 0; mi < 4; ++mi) {
            int gr = bm0 + wr * 64 + mi * 16 + lm;
            #pragma unroll
            for (int ks = 0; ks < 4; ++ks) {
                short8 t = {};
                if (gr < NN) {
                    f32x4 a0 = *(const f32x4*)(xf + (size_t)gr * DD + ks * 32 + lg * 8);
                    f32x4 a1 = *(const f32x4*)(xf + (size_t)gr * DD + ks * 32 + lg * 8 + 4);
                    t[0] = (short)f2bf(a0.x); t[1] = (short)f2bf(a0.y);
                    t[2] = (short)f2bf(a0.z); t[3] = (short)f2bf(a0.w);
                    t[4] = (short)f2bf(a1.x); t[5] = (short)f2bf(a1.y);
                    t[6] = (short)f2bf(a1.z); t[7] = (short)f2bf(a1.w);
                }
                af[mi][ks] = t;
            }
        }
    } else {
        #pragma unroll
        for (int mi = 0; mi < 4; ++mi) {
            int gr = bm0 + wr * 64 + mi * 16 + lm;
            #pragma unroll
            for (int ks = 0; ks < 4; ++ks) {
                short8 t = {};
                if (gr < NN) t = *(const short8*)(hb + (size_t)gr * DD + ks * 32 + lg * 8);
                af[mi][ks] = t;
            }
        }
    }
    for (int cb = 0; cb < 8; ++cb) {
        f32x4 acc[4][4] = {};
        #pragma unroll
        for (int ks = 0; ks < 4; ++ks) {
            short8 bfr[4];
            #pragma unroll
            for (int ni = 0; ni < 4; ++ni)
                bfr[ni] = *(const short8*)(Wt2 + (size_t)(cb * 128 + wc * 64 + ni * 16 + lm) * DD
                                           + ks * 32 + lg * 8);
            #pragma unroll
            for (int mi = 0; mi < 4; ++mi)
                #pragma unroll
                for (int ni = 0; ni < 4; ++ni)
                    acc[mi][ni] = __builtin_amdgcn_mfma_f32_16x16x32_bf16(af[mi][ks], bfr[ni], acc[mi][ni], 0, 0, 0);
        }
        #pragma unroll
        for (int mi = 0; mi < 4; ++mi) {
            #pragma unroll
            for (int v = 0; v < 4; ++v) {
                int gm = bm0 + wr * 64 + mi * 16 + lg * 4 + v;
                if (gm >= NN) continue;
                #pragma unroll
                for (int ni = 0; ni < 4; ++ni) {
                    int j = cb * 128 + wc * 64 + ni * 16 + lm;
                    P[(size_t)gm * 1024 + j] = f2bf(acc[mi][ni][v]);
                }
            }
        }
    }
}

// ---- gather: wave/node, 4 edge streams (quarter-wave), depth-3 per stream ----
// lane = q*16 + l4; stream q walks edges q, q+4, ...; lane covers 16B = cols l4*8..+7.
#define PR4(r) (((const u32x4*)(P + (size_t)(((((r).x & 0xFFFF) << 3) | ((r).x >> 16))) * DD)) + l4)
__global__ __launch_bounds__(256) void gather_p(
        const unsigned short* __restrict__ P,    // [N][8][128] bf16
        const int2* __restrict__ segd,           // [N] {start,count}
        const int2* __restrict__ edges,          // +16 zeroed slop records
        const float* __restrict__ bias,
        const unsigned short* __restrict__ hb_in,// bf16 residual (l>0)
        const float* __restrict__ xf,            // fp32 residual (l==0) or null
        unsigned short* __restrict__ hb_out,     // bf16 [N][128] (l<2)
        float* __restrict__ nf,                  // fp32 [N][128] (last layer)
        int last) {
    int tid = threadIdx.x;
    int wv = tid >> 6, lane = tid & 63;
    int q = lane >> 4, l4 = lane & 15;
    int node = blockIdx.x * 4 + wv;              // 12500*4 = 50000 exact
    int2 sd = segd[node];
    int st = sd.x, cnt = sd.y;
    int base = st + q;
    int mmax = (cnt + 3) >> 2;

    float ac[8] = {};
    int2 r0 = edges[base];
    int2 r1 = edges[base + 4];
    int2 r2 = edges[base + 8];
    u32x4 hv0 = *PR4(r0);
    u32x4 hv1 = *PR4(r1);
    for (int i = 0; i < mmax; ++i) {
        int2 r3 = edges[base + 4 * i + 12];
        u32x4 hv2 = *PR4(r2);
        if (q + 4 * i < cnt) {
            float w = __int_as_float(r0.y);
            #pragma unroll
            for (int j = 0; j < 4; ++j) {
                ac[2 * j]     += bf2f((unsigned short)(hv0[j] & 0xFFFF)) * w;
                ac[2 * j + 1] += bf2f((unsigned short)(hv0[j] >> 16)) * w;
            }
        }
        r0 = r1; r1 = r2; r2 = r3;
        hv0 = hv1; hv1 = hv2;
    }
    // combine 4 streams
    #pragma unroll
    for (int j = 0; j < 8; ++j) {
        ac[j] += __shfl_xor(ac[j], 16);
        ac[j] += __shfl_xor(ac[j], 32);
    }
    if (q == 0) {
        u32x4 hs = ((const u32x4*)(P + ((size_t)node * 8 + 7) * DD))[l4];
        f32x4 b0 = ((const f32x4*)bias)[l4 * 2];
        f32x4 b1 = ((const f32x4*)bias)[l4 * 2 + 1];
        float hp[8];
        if (xf) {
            f32x4 h0 = ((const f32x4*)xf)[(size_t)node * 32 + l4 * 2];
            f32x4 h1 = ((const f32x4*)xf)[(size_t)node * 32 + l4 * 2 + 1];
            hp[0] = h0.x; hp[1] = h0.y; hp[2] = h0.z; hp[3] = h0.w;
            hp[4] = h1.x; hp[5] = h1.y; hp[6] = h1.z; hp[7] = h1.w;
        } else {
            u32x4 hpv = ((const u32x4*)hb_in)[(size_t)node * 16 + l4];
            #pragma unroll
            for (int j = 0; j < 4; ++j) {
                hp[2 * j]     = bf2f((unsigned short)(hpv[j] & 0xFFFF));
                hp[2 * j + 1] = bf2f((unsigned short)(hpv[j] >> 16));
            }
        }
        float bb[8] = { b0.x, b0.y, b0.z, b0.w, b1.x, b1.y, b1.z, b1.w };
        float o[8];
        #pragma unroll
        for (int j = 0; j < 4; ++j) {
            o[2 * j]     = fmaxf(ac[2 * j]     + bf2f((unsigned short)(hs[j] & 0xFFFF)) + bb[2 * j],     0.f) + hp[2 * j];
            o[2 * j + 1] = fmaxf(ac[2 * j + 1] + bf2f((unsigned short)(hs[j] >> 16))    + bb[2 * j + 1], 0.f) + hp[2 * j + 1];
        }
        if (last) {
            ((f32x4*)nf)[(size_t)node * 32 + l4 * 2]     = (f32x4){o[0], o[1], o[2], o[3]};
            ((f32x4*)nf)[(size_t)node * 32 + l4 * 2 + 1] = (f32x4){o[4], o[5], o[6], o[7]};
        } else {
            u32x4 pk;
            #pragma unroll
            for (int j = 0; j < 4; ++j)
                pk[j] = (unsigned)f2bf(o[2 * j]) | ((unsigned)f2bf(o[2 * j + 1]) << 16);
            ((u32x4*)hb_out)[(size_t)node * 16 + l4] = pk;
        }
    }
}

// Parallel readout: block = 128 nodes, 8 row-streams x 32 lanes (f32x4 cols).
__global__ __launch_bounds__(256) void readout(const float* __restrict__ h,
                                               const int* __restrict__ n2g,
                                               float* __restrict__ gf) {
    int c0 = blockIdx.x * 128;
    int rg = threadIdx.x >> 5, d4 = threadIdx.x & 31;
    f32x4 acc = {0.f, 0.f, 0.f, 0.f};
    int cur = -1;
    #pragma unroll 4
    for (int it = 0; it < 16; ++it) {
        int row = c0 + it * 8 + rg;
        if (row >= NN) break;
        int g = n2g[row];
        if (g != cur) {
            if (cur >= 0) {
                atomicAdd(&gf[cur * DD + d4 * 4 + 0], acc.x);
                atomicAdd(&gf[cur * DD + d4 * 4 + 1], acc.y);
                atomicAdd(&gf[cur * DD + d4 * 4 + 2], acc.z);
                atomicAdd(&gf[cur * DD + d4 * 4 + 3], acc.w);
            }
            cur = g;
            acc = (f32x4){0.f, 0.f, 0.f, 0.f};
        }
        acc += ((const f32x4*)h)[(size_t)row * 32 + d4];
    }
    if (cur >= 0) {
        atomicAdd(&gf[cur * DD + d4 * 4 + 0], acc.x);
        atomicAdd(&gf[cur * DD + d4 * 4 + 1], acc.y);
        atomicAdd(&gf[cur * DD + d4 * 4 + 2], acc.z);
        atomicAdd(&gf[cur * DD + d4 * 4 + 3], acc.w);
    }
}

extern "C" void kernel_launch(void* const* d_in, const int* in_sizes, int n_in,
                              void* d_out, int out_size, void* d_ws, size_t ws_size,
                              hipStream_t stream) {
    const float* x      = (const float*)d_in[0];
    const int* node_in  = (const int*)d_in[1];
    const int* node_out = (const int*)d_in[2];
    const int* relation = (const int*)d_in[3];
    const float* ew     = (const float*)d_in[4];
    const int* n2g      = (const int*)d_in[5];

    float* out = (float*)d_out;
    float* gf = out;                       // [G,D]
    float* nf = out + GG * DD;             // [N,D]

    char* ws = (char*)d_ws;
    size_t off = 0;
    unsigned short* P  = (unsigned short*)(ws + off); off += (size_t)NN * 1024 * 2;   // 102.4 MB
    unsigned short* hb0 = (unsigned short*)(ws + off); off += (size_t)NN * DD * 2;    // 12.8 MB
    unsigned short* hb1 = (unsigned short*)(ws + off); off += (size_t)NN * DD * 2;    // 12.8 MB
    unsigned short* Wt2 = (unsigned short*)(ws + off); off += (size_t)3 * 1024 * DD * 2;
    float* bias = (float*)(ws + off);            off += 3 * DD * 4;
    int* counts = (int*)(ws + off);              off += (size_t)NN * 4;
    int* cursor = (int*)(ws + off);              off += (size_t)NN * 4;
    int* start  = (int*)(ws + off);              off += (size_t)NN * 4;
    int2* segd  = (int2*)(ws + off);             off += (size_t)NN * 8;
    int* bsum   = (int*)(ws + off);              off += 64 * 4;
    int2* edges = (int2*)(ws + off);             off += (size_t)(EE + 16) * 8;        // +slop

    prep_w2<<<3 * 512, 256, 0, stream>>>(
        (const float*)d_in[10], (const float*)d_in[14], (const float*)d_in[18],
        (const float*)d_in[8],  (const float*)d_in[12], (const float*)d_in[16],
        (const float*)d_in[11], (const float*)d_in[15], (const float*)d_in[19],
        (const float*)d_in[9],  (const float*)d_in[13], (const float*)d_in[17],
        Wt2, bias);

    // CSR build (node-grouped; layer-invariant)
    zero_misc<<<(2 * NN + 255) / 256, 256, 0, stream>>>(counts, (int*)(edges + EE), gf);
    hist<<<(EE + 255) / 256, 256, 0, stream>>>(node_out, counts);
    scan1<<<NB1, 256, 0, stream>>>(counts, start, bsum);
    scan2<<<1, 64, 0, stream>>>(bsum);
    scan3<<<(NN + 255) / 256, 256, 0, stream>>>(start, bsum, counts, segd);
    fill<<<(EE + 255) / 256, 256, 0, stream>>>(node_in, node_out, relation, ew,
                                               segd, cursor, edges);

    // layer 0: read x directly; layers 1,2: bf16 ping-pong hb1 -> hb0
    gemm_p<<<(NN + 127) / 128, 256, 0, stream>>>(nullptr, x, Wt2, P);
    gather_p<<<NN / 4, 256, 0, stream>>>(P, segd, edges, bias, nullptr, x,
                                         hb1, nf, 0);
    gemm_p<<<(NN + 127) / 128, 256, 0, stream>>>(hb1, nullptr, Wt2 + (size_t)1024 * DD, P);
    gather_p<<<NN / 4, 256, 0, stream>>>(P, segd, edges, bias + DD, hb1, nullptr,
                                         hb0, nf, 0);
    gemm_p<<<(NN + 127) / 128, 256, 0, stream>>>(hb0, nullptr, Wt2 + (size_t)2048 * DD, P);
    gather_p<<<NN / 4, 256, 0, stream>>>(P, segd, edges, bias + 2 * DD, hb0, nullptr,
                                         nullptr, nf, 1);

    readout<<<(NN + 127) / 128, 256, 0, stream>>>(nf, n2g, gf);
}

// Round 24
// 358.854 us; speedup vs baseline: 1.3347x; 1.0001x over previous
//
#include <hip/hip_runtime.h>
#include <hip/hip_bf16.h>

#define NN 50000
#define EE 600000
#define DD 128
#define RR 7
#define GG 32
#define NB1 ((NN + 1023) / 1024)   // 49 scan blocks

typedef float f32x4 __attribute__((ext_vector_type(4)));
typedef short short8 __attribute__((ext_vector_type(8)));
typedef unsigned u32x4 __attribute__((ext_vector_type(4)));

static __device__ __forceinline__ unsigned short f2bf(float f) {
    union { float f; unsigned u; } v; v.f = f;
    unsigned r = v.u + 0x7fff + ((v.u >> 16) & 1);
    return (unsigned short)(r >> 16);
}
static __device__ __forceinline__ float bf2f(unsigned short u) {
    union { unsigned u; float f; } v; v.u = ((unsigned)u) << 16;
    return v.f;
}

// ---- weights prep, all 3 layers in one launch ----
__global__ void prep_w2(const float* lw0, const float* lw1, const float* lw2,
                        const float* sw0, const float* sw1, const float* sw2,
                        const float* lb0, const float* lb1, const float* lb2,
                        const float* sb0, const float* sb1, const float* sb2,
                        unsigned short* __restrict__ Wt2, float* __restrict__ bias) {
    int l = blockIdx.x >> 9;                    // 512 blocks per layer
    int idx = (blockIdx.x & 511) * 256 + threadIdx.x;
    const float* lin_w = l == 0 ? lw0 : (l == 1 ? lw1 : lw2);
    const float* sl_w  = l == 0 ? sw0 : (l == 1 ? sw1 : sw2);
    if (idx < DD) {
        const float* lin_b = l == 0 ? lb0 : (l == 1 ? lb1 : lb2);
        const float* sl_b  = l == 0 ? sb0 : (l == 1 ? sb1 : sb2);
        bias[l * DD + idx] = lin_b[idx] + sl_b[idx];
    }
    if (idx >= 1024 * DD) return;
    int j = idx >> 7;                  // output col: slot*128 + dout
    int k = idx & 127;                 // din
    int slot = j >> 7, dout = j & 127;
    float w = (slot < 7) ? lin_w[(slot * DD + k) * DD + dout] : sl_w[k * DD + dout];
    Wt2[(size_t)l * 1024 * DD + (size_t)j * DD + k] = f2bf(w);
}

// ---- zero: counts+cursor (2*NN ints), slop (32 ints), gf (GG*DD floats) ----
__global__ void zero_misc(int* __restrict__ cc, int* __restrict__ slop, float* __restrict__ gf) {
    int i = blockIdx.x * 256 + threadIdx.x;
    if (i < 2 * NN) cc[i] = 0;
    if (i < 32) slop[i] = 0;
    if (i < GG * DD) gf[i] = 0.f;
}

__global__ void hist(const int* __restrict__ node_out, int* __restrict__ counts) {
    int e = blockIdx.x * 256 + threadIdx.x;
    if (e >= EE) return;
    atomicAdd(&counts[node_out[e]], 1);
}

__global__ __launch_bounds__(256) void scan1(const int* __restrict__ counts,
                                             int* __restrict__ start, int* __restrict__ bsum) {
    __shared__ int s[256];
    int tid = threadIdx.x;
    int base = blockIdx.x * 1024 + tid * 4;
    int v[4], sum = 0;
    #pragma unroll
    for (int j = 0; j < 4; ++j) {
        v[j] = (base + j < NN) ? counts[base + j] : 0;
        sum += v[j];
    }
    s[tid] = sum; __syncthreads();
    for (int off = 1; off < 256; off <<= 1) {
        int t = (tid >= off) ? s[tid - off] : 0;
        __syncthreads();
        s[tid] += t;
        __syncthreads();
    }
    int run = s[tid] - sum;
    if (tid == 255) bsum[blockIdx.x] = s[255];
    #pragma unroll
    for (int j = 0; j < 4; ++j) {
        if (base + j < NN) { start[base + j] = run; run += v[j]; }
    }
}

__global__ __launch_bounds__(64) void scan2(int* __restrict__ bsum) {
    __shared__ int s[64];
    int tid = threadIdx.x;
    int v = (tid < NB1) ? bsum[tid] : 0;
    s[tid] = v; __syncthreads();
    for (int off = 1; off < 64; off <<= 1) {
        int t = (tid >= off) ? s[tid - off] : 0;
        __syncthreads();
        s[tid] += t;
        __syncthreads();
    }
    if (tid < NB1) bsum[tid] = s[tid] - v;
}

__global__ void scan3(const int* __restrict__ start, const int* __restrict__ bsum,
                      const int* __restrict__ counts, int2* __restrict__ segd) {
    int i = blockIdx.x * 256 + threadIdx.x;
    if (i < NN) segd[i] = make_int2(start[i] + bsum[i >> 10], counts[i]);
}

// record: x = (rel << 16) | node_in, y = weight bits.  Node-grouped.
__global__ void fill(const int* __restrict__ node_in, const int* __restrict__ node_out,
                     const int* __restrict__ rel, const float* __restrict__ ew,
                     const int2* __restrict__ segd, int* __restrict__ cursor,
                     int2* __restrict__ edges) {
    int e = blockIdx.x * 256 + threadIdx.x;
    if (e >= EE) return;
    int seg = node_out[e];
    int pos = segd[seg].x + atomicAdd(&cursor[seg], 1);
    edges[pos] = make_int2((rel[e] << 16) | node_in[e], __float_as_int(ew[e]));
}

// ---- dense GEMM (r12 form): BM=128, A in regs, direct stores.
// Layer 0 reads fp32 x directly (xf != nullptr); else bf16 hb.
__global__ __launch_bounds__(256) void gemm_p(
        const unsigned short* __restrict__ hb,   // [N][128] bf16 (l>0)
        const float* __restrict__ xf,            // [N][128] fp32 (l==0) or null
        const unsigned short* __restrict__ Wt2,  // [1024][128] bf16
        unsigned short* __restrict__ P) {        // [N][1024] bf16
    int tid = threadIdx.x;
    int wid = tid >> 6, lane = tid & 63;
    int wr = wid >> 1, wc = wid & 1;
    int lm = lane & 15, lg = lane >> 4;
    int bm0 = blockIdx.x * 128;

    short8 af[4][4];
    if (xf) {
        #pragma unroll
        for (int mi = 0; mi < 4; ++mi) {
            int gr = bm0 + wr * 64 + mi * 16 + lm;
            #pragma unroll
            for (int ks = 0; ks < 4; ++ks) {
                short8 t = {};
                if (gr < NN) {
                    f32x4 a0 = *(const f32x4*)(xf + (size_t)gr * DD + ks * 32 + lg * 8);
                    f32x4 a1 = *(const f32x4*)(xf + (size_t)gr * DD + ks * 32 + lg * 8 + 4);
                    t[0] = (short)f2bf(a0.x); t[1] = (short)f2bf(a0.y);
                    t[2] = (short)f2bf(a0.z); t[3] = (short)f2bf(a0.w);
                    t[4] = (short)f2bf(a1.x); t[5] = (short)f2bf(a1.y);
                    t[6] = (short)f2bf(a1.z); t[7] = (short)f2bf(a1.w);
                }
                af[mi][ks] = t;
            }
        }
    } else {
        #pragma unroll
        for (int mi = 0; mi < 4; ++mi) {
            int gr = bm0 + wr * 64 + mi * 16 + lm;
            #pragma unroll
            for (int ks = 0; ks < 4; ++ks) {
                short8 t = {};
                if (gr < NN) t = *(const short8*)(hb + (size_t)gr * DD + ks * 32 + lg * 8);
                af[mi][ks] = t;
            }
        }
    }
    for (int cb = 0; cb < 8; ++cb) {
        f32x4 acc[4][4] = {};
        #pragma unroll
        for (int ks = 0; ks < 4; ++ks) {
            short8 bfr[4];
            #pragma unroll
            for (int ni = 0; ni < 4; ++ni)
                bfr[ni] = *(const short8*)(Wt2 + (size_t)(cb * 128 + wc * 64 + ni * 16 + lm) * DD
                                           + ks * 32 + lg * 8);
            #pragma unroll
            for (int mi = 0; mi < 4; ++mi)
                #pragma unroll
                for (int ni = 0; ni < 4; ++ni)
                    acc[mi][ni] = __builtin_amdgcn_mfma_f32_16x16x32_bf16(af[mi][ks], bfr[ni], acc[mi][ni], 0, 0, 0);
        }
        #pragma unroll
        for (int mi = 0; mi < 4; ++mi) {
            #pragma unroll
            for (int v = 0; v < 4; ++v) {
                int gm = bm0 + wr * 64 + mi * 16 + lg * 4 + v;
                if (gm >= NN) continue;
                #pragma unroll
                for (int ni = 0; ni < 4; ++ni) {
                    int j = cb * 128 + wc * 64 + ni * 16 + lm;
                    P[(size_t)gm * 1024 + j] = f2bf(acc[mi][ni][v]);
                }
            }
        }
    }
}

// ---- gather: wave/node, 4 edge streams (quarter-wave), depth-3 per stream ----
// lane = q*16 + l4; stream q walks edges q, q+4, ...; lane covers 16B = cols l4*8..+7.
#define PR4(r) (((const u32x4*)(P + (size_t)(((((r).x & 0xFFFF) << 3) | ((r).x >> 16))) * DD)) + l4)
__global__ __launch_bounds__(256) void gather_p(
        const unsigned short* __restrict__ P,    // [N][8][128] bf16
        const int2* __restrict__ segd,           // [N] {start,count}
        const int2* __restrict__ edges,          // +16 zeroed slop records
        const float* __restrict__ bias,
        const unsigned short* __restrict__ hb_in,// bf16 residual (l>0)
        const float* __restrict__ xf,            // fp32 residual (l==0) or null
        unsigned short* __restrict__ hb_out,     // bf16 [N][128] (l<2)
        float* __restrict__ nf,                  // fp32 [N][128] (last layer)
        int last) {
    int tid = threadIdx.x;
    int wv = tid >> 6, lane = tid & 63;
    int q = lane >> 4, l4 = lane & 15;
    int node = blockIdx.x * 4 + wv;              // 12500*4 = 50000 exact
    int2 sd = segd[node];
    int st = sd.x, cnt = sd.y;
    int base = st + q;
    int mmax = (cnt + 3) >> 2;

    float ac[8] = {};
    int2 r0 = edges[base];
    int2 r1 = edges[base + 4];
    int2 r2 = edges[base + 8];
    u32x4 hv0 = *PR4(r0);
    u32x4 hv1 = *PR4(r1);
    for (int i = 0; i < mmax; ++i) {
        int2 r3 = edges[base + 4 * i + 12];
        u32x4 hv2 = *PR4(r2);
        if (q + 4 * i < cnt) {
            float w = __int_as_float(r0.y);
            #pragma unroll
            for (int j = 0; j < 4; ++j) {
                ac[2 * j]     += bf2f((unsigned short)(hv0[j] & 0xFFFF)) * w;
                ac[2 * j + 1] += bf2f((unsigned short)(hv0[j] >> 16)) * w;
            }
        }
        r0 = r1; r1 = r2; r2 = r3;
        hv0 = hv1; hv1 = hv2;
    }
    // combine 4 streams
    #pragma unroll
    for (int j = 0; j < 8; ++j) {
        ac[j] += __shfl_xor(ac[j], 16);
        ac[j] += __shfl_xor(ac[j], 32);
    }
    if (q == 0) {
        u32x4 hs = ((const u32x4*)(P + ((size_t)node * 8 + 7) * DD))[l4];
        f32x4 b0 = ((const f32x4*)bias)[l4 * 2];
        f32x4 b1 = ((const f32x4*)bias)[l4 * 2 + 1];
        float hp[8];
        if (xf) {
            f32x4 h0 = ((const f32x4*)xf)[(size_t)node * 32 + l4 * 2];
            f32x4 h1 = ((const f32x4*)xf)[(size_t)node * 32 + l4 * 2 + 1];
            hp[0] = h0.x; hp[1] = h0.y; hp[2] = h0.z; hp[3] = h0.w;
            hp[4] = h1.x; hp[5] = h1.y; hp[6] = h1.z; hp[7] = h1.w;
        } else {
            u32x4 hpv = ((const u32x4*)hb_in)[(size_t)node * 16 + l4];
            #pragma unroll
            for (int j = 0; j < 4; ++j) {
                hp[2 * j]     = bf2f((unsigned short)(hpv[j] & 0xFFFF));
                hp[2 * j + 1] = bf2f((unsigned short)(hpv[j] >> 16));
            }
        }
        float bb[8] = { b0.x, b0.y, b0.z, b0.w, b1.x, b1.y, b1.z, b1.w };
        float o[8];
        #pragma unroll
        for (int j = 0; j < 4; ++j) {
            o[2 * j]     = fmaxf(ac[2 * j]     + bf2f((unsigned short)(hs[j] & 0xFFFF)) + bb[2 * j],     0.f) + hp[2 * j];
            o[2 * j + 1] = fmaxf(ac[2 * j + 1] + bf2f((unsigned short)(hs[j] >> 16))    + bb[2 * j + 1], 0.f) + hp[2 * j + 1];
        }
        if (last) {
            ((f32x4*)nf)[(size_t)node * 32 + l4 * 2]     = (f32x4){o[0], o[1], o[2], o[3]};
            ((f32x4*)nf)[(size_t)node * 32 + l4 * 2 + 1] = (f32x4){o[4], o[5], o[6], o[7]};
        } else {
            u32x4 pk;
            #pragma unroll
            for (int j = 0; j < 4; ++j)
                pk[j] = (unsigned)f2bf(o[2 * j]) | ((unsigned)f2bf(o[2 * j + 1]) << 16);
            ((u32x4*)hb_out)[(size_t)node * 16 + l4] = pk;
        }
    }
}

// Parallel readout: block = 128 nodes, 8 row-streams x 32 lanes (f32x4 cols).
__global__ __launch_bounds__(256) void readout(const float* __restrict__ h,
                                               const int* __restrict__ n2g,
                                               float* __restrict__ gf) {
    int c0 = blockIdx.x * 128;
    int rg = threadIdx.x >> 5, d4 = threadIdx.x & 31;
    f32x4 acc = {0.f, 0.f, 0.f, 0.f};
    int cur = -1;
    #pragma unroll 4
    for (int it = 0; it < 16; ++it) {
        int row = c0 + it * 8 + rg;
        if (row >= NN) break;
        int g = n2g[row];
        if (g != cur) {
            if (cur >= 0) {
                atomicAdd(&gf[cur * DD + d4 * 4 + 0], acc.x);
                atomicAdd(&gf[cur * DD + d4 * 4 + 1], acc.y);
                atomicAdd(&gf[cur * DD + d4 * 4 + 2], acc.z);
                atomicAdd(&gf[cur * DD + d4 * 4 + 3], acc.w);
            }
            cur = g;
            acc = (f32x4){0.f, 0.f, 0.f, 0.f};
        }
        acc += ((const f32x4*)h)[(size_t)row * 32 + d4];
    }
    if (cur >= 0) {
        atomicAdd(&gf[cur * DD + d4 * 4 + 0], acc.x);
        atomicAdd(&gf[cur * DD + d4 * 4 + 1], acc.y);
        atomicAdd(&gf[cur * DD + d4 * 4 + 2], acc.z);
        atomicAdd(&gf[cur * DD + d4 * 4 + 3], acc.w);
    }
}

extern "C" void kernel_launch(void* const* d_in, const int* in_sizes, int n_in,
                              void* d_out, int out_size, void* d_ws, size_t ws_size,
                              hipStream_t stream) {
    const float* x      = (const float*)d_in[0];
    const int* node_in  = (const int*)d_in[1];
    const int* node_out = (const int*)d_in[2];
    const int* relation = (const int*)d_in[3];
    const float* ew     = (const float*)d_in[4];
    const int* n2g      = (const int*)d_in[5];

    float* out = (float*)d_out;
    float* gf = out;                       // [G,D]
    float* nf = out + GG * DD;             // [N,D]

    char* ws = (char*)d_ws;
    size_t off = 0;
    unsigned short* P  = (unsigned short*)(ws + off); off += (size_t)NN * 1024 * 2;   // 102.4 MB
    unsigned short* hb0 = (unsigned short*)(ws + off); off += (size_t)NN * DD * 2;    // 12.8 MB
    unsigned short* hb1 = (unsigned short*)(ws + off); off += (size_t)NN * DD * 2;    // 12.8 MB
    unsigned short* Wt2 = (unsigned short*)(ws + off); off += (size_t)3 * 1024 * DD * 2;
    float* bias = (float*)(ws + off);            off += 3 * DD * 4;
    int* counts = (int*)(ws + off);              off += (size_t)NN * 4;
    int* cursor = (int*)(ws + off);              off += (size_t)NN * 4;
    int* start  = (int*)(ws + off);              off += (size_t)NN * 4;
    int2* segd  = (int2*)(ws + off);             off += (size_t)NN * 8;
    int* bsum   = (int*)(ws + off);              off += 64 * 4;
    int2* edges = (int2*)(ws + off);             off += (size_t)(EE + 16) * 8;        // +slop

    prep_w2<<<3 * 512, 256, 0, stream>>>(
        (const float*)d_in[10], (const float*)d_in[14], (const float*)d_in[18],
        (const float*)d_in[8],  (const float*)d_in[12], (const float*)d_in[16],
        (const float*)d_in[11], (const float*)d_in[15], (const float*)d_in[19],
        (const float*)d_in[9],  (const float*)d_in[13], (const float*)d_in[17],
        Wt2, bias);

    // CSR build (node-grouped; layer-invariant)
    zero_misc<<<(2 * NN + 255) / 256, 256, 0, stream>>>(counts, (int*)(edges + EE), gf);
    hist<<<(EE + 255) / 256, 256, 0, stream>>>(node_out, counts);
    scan1<<<NB1, 256, 0, stream>>>(counts, start, bsum);
    scan2<<<1, 64, 0, stream>>>(bsum);
    scan3<<<(NN + 255) / 256, 256, 0, stream>>>(start, bsum, counts, segd);
    fill<<<(EE + 255) / 256, 256, 0, stream>>>(node_in, node_out, relation, ew,
                                               segd, cursor, edges);

    // layer 0: read x directly; layers 1,2: bf16 ping-pong hb1 -> hb0
    gemm_p<<<(NN + 127) / 128, 256, 0, stream>>>(nullptr, x, Wt2, P);
    gather_p<<<NN / 4, 256, 0, stream>>>(P, segd, edges, bias, nullptr, x,
                                         hb1, nf, 0);
    gemm_p<<<(NN + 127) / 128, 256, 0, stream>>>(hb1, nullptr, Wt2 + (size_t)1024 * DD, P);
    gather_p<<<NN / 4, 256, 0, stream>>>(P, segd, edges, bias + DD, hb1, nullptr,
                                         hb0, nf, 0);
    gemm_p<<<(NN + 127) / 128, 256, 0, stream>>>(hb0, nullptr, Wt2 + (size_t)2048 * DD, P);
    gather_p<<<NN / 4, 256, 0, stream>>>(P, segd, edges, bias + 2 * DD, hb0, nullptr,
                                         nullptr, nf, 1);

    readout<<<(NN + 127) / 128, 256, 0, stream>>>(nf, n2g, gf);
}

// Round 25
// 355.379 us; speedup vs baseline: 1.3478x; 1.0098x over previous
//
#include <hip/hip_runtime.h>
#include <hip/hip_bf16.h>

#define NN 50000
#define EE 600000
#define DD 128
#define RR 7
#define GG 32
#define NB1 ((NN + 1023) / 1024)   // 49 scan blocks

typedef float f32x4 __attribute__((ext_vector_type(4)));
typedef short short8 __attribute__((ext_vector_type(8)));
typedef unsigned u32x4 __attribute__((ext_vector_type(4)));

static __device__ __forceinline__ unsigned short f2bf(float f) {
    union { float f; unsigned u; } v; v.f = f;
    unsigned r = v.u + 0x7fff + ((v.u >> 16) & 1);
    return (unsigned short)(r >> 16);
}
static __device__ __forceinline__ float bf2f(unsigned short u) {
    union { unsigned u; float f; } v; v.u = ((unsigned)u) << 16;
    return v.f;
}

// ---- weights prep, all 3 layers in one launch ----
__global__ void prep_w2(const float* lw0, const float* lw1, const float* lw2,
                        const float* sw0, const float* sw1, const float* sw2,
                        const float* lb0, const float* lb1, const float* lb2,
                        const float* sb0, const float* sb1, const float* sb2,
                        unsigned short* __restrict__ Wt2, float* __restrict__ bias) {
    int l = blockIdx.x >> 9;                    // 512 blocks per layer
    int idx = (blockIdx.x & 511) * 256 + threadIdx.x;
    const float* lin_w = l == 0 ? lw0 : (l == 1 ? lw1 : lw2);
    const float* sl_w  = l == 0 ? sw0 : (l == 1 ? sw1 : sw2);
    if (idx < DD) {
        const float* lin_b = l == 0 ? lb0 : (l == 1 ? lb1 : lb2);
        const float* sl_b  = l == 0 ? sb0 : (l == 1 ? sb1 : sb2);
        bias[l * DD + idx] = lin_b[idx] + sl_b[idx];
    }
    if (idx >= 1024 * DD) return;
    int j = idx >> 7;                  // output col: slot*128 + dout
    int k = idx & 127;                 // din
    int slot = j >> 7, dout = j & 127;
    float w = (slot < 7) ? lin_w[(slot * DD + k) * DD + dout] : sl_w[k * DD + dout];
    Wt2[(size_t)l * 1024 * DD + (size_t)j * DD + k] = f2bf(w);
}

// ---- zero: counts+cursor (2*NN ints), slop (32 ints), gf (GG*DD floats) ----
__global__ void zero_misc(int* __restrict__ cc, int* __restrict__ slop, float* __restrict__ gf) {
    int i = blockIdx.x * 256 + threadIdx.x;
    if (i < 2 * NN) cc[i] = 0;
    if (i < 32) slop[i] = 0;
    if (i < GG * DD) gf[i] = 0.f;
}

__global__ void hist(const int* __restrict__ node_out, int* __restrict__ counts) {
    int e = blockIdx.x * 256 + threadIdx.x;
    if (e >= EE) return;
    atomicAdd(&counts[node_out[e]], 1);
}

__global__ __launch_bounds__(256) void scan1(const int* __restrict__ counts,
                                             int* __restrict__ start, int* __restrict__ bsum) {
    __shared__ int s[256];
    int tid = threadIdx.x;
    int base = blockIdx.x * 1024 + tid * 4;
    int v[4], sum = 0;
    #pragma unroll
    for (int j = 0; j < 4; ++j) {
        v[j] = (base + j < NN) ? counts[base + j] : 0;
        sum += v[j];
    }
    s[tid] = sum; __syncthreads();
    for (int off = 1; off < 256; off <<= 1) {
        int t = (tid >= off) ? s[tid - off] : 0;
        __syncthreads();
        s[tid] += t;
        __syncthreads();
    }
    int run = s[tid] - sum;
    if (tid == 255) bsum[blockIdx.x] = s[255];
    #pragma unroll
    for (int j = 0; j < 4; ++j) {
        if (base + j < NN) { start[base + j] = run; run += v[j]; }
    }
}

__global__ __launch_bounds__(64) void scan2(int* __restrict__ bsum) {
    __shared__ int s[64];
    int tid = threadIdx.x;
    int v = (tid < NB1) ? bsum[tid] : 0;
    s[tid] = v; __syncthreads();
    for (int off = 1; off < 64; off <<= 1) {
        int t = (tid >= off) ? s[tid - off] : 0;
        __syncthreads();
        s[tid] += t;
        __syncthreads();
    }
    if (tid < NB1) bsum[tid] = s[tid] - v;
}

__global__ void scan3(const int* __restrict__ start, const int* __restrict__ bsum,
                      const int* __restrict__ counts, int2* __restrict__ segd) {
    int i = blockIdx.x * 256 + threadIdx.x;
    if (i < NN) segd[i] = make_int2(start[i] + bsum[i >> 10], counts[i]);
}

// record: x = (rel << 16) | node_in, y = weight bits.  Node-grouped.
__global__ void fill(const int* __restrict__ node_in, const int* __restrict__ node_out,
                     const int* __restrict__ rel, const float* __restrict__ ew,
                     const int2* __restrict__ segd, int* __restrict__ cursor,
                     int2* __restrict__ edges) {
    int e = blockIdx.x * 256 + threadIdx.x;
    if (e >= EE) return;
    int seg = node_out[e];
    int pos = segd[seg].x + atomicAdd(&cursor[seg], 1);
    edges[pos] = make_int2((rel[e] << 16) | node_in[e], __float_as_int(ew[e]));
}

// ---- dense GEMM, bf16 input (layers 1,2): exact r12/r22 body, 49.8 µs ----
__global__ __launch_bounds__(256) void gemm_pb(
        const unsigned short* __restrict__ hb,   // [N][128] bf16
        const unsigned short* __restrict__ Wt2,  // [1024][128] bf16
        unsigned short* __restrict__ P) {        // [N][1024] bf16
    int tid = threadIdx.x;
    int wid = tid >> 6, lane = tid & 63;
    int wr = wid >> 1, wc = wid & 1;
    int lm = lane & 15, lg = lane >> 4;
    int bm0 = blockIdx.x * 128;

    short8 af[4][4];
    #pragma unroll
    for (int mi = 0; mi < 4; ++mi) {
        int gr = bm0 + wr * 64 + mi * 16 + lm;
        #pragma unroll
        for (int ks = 0; ks < 4; ++ks) {
            short8 t = {};
            if (gr < NN) t = *(const short8*)(hb + (size_t)gr * DD + ks * 32 + lg * 8);
            af[mi][ks] = t;
        }
    }
    for (int cb = 0; cb < 8; ++cb) {
        f32x4 acc[4][4] = {};
        #pragma unroll
        for (int ks = 0; ks < 4; ++ks) {
            short8 bfr[4];
            #pragma unroll
            for (int ni = 0; ni < 4; ++ni)
                bfr[ni] = *(const short8*)(Wt2 + (size_t)(cb * 128 + wc * 64 + ni * 16 + lm) * DD
                                           + ks * 32 + lg * 8);
            #pragma unroll
            for (int mi = 0; mi < 4; ++mi)
                #pragma unroll
                for (int ni = 0; ni < 4; ++ni)
                    acc[mi][ni] = __builtin_amdgcn_mfma_f32_16x16x32_bf16(af[mi][ks], bfr[ni], acc[mi][ni], 0, 0, 0);
        }
        #pragma unroll
        for (int mi = 0; mi < 4; ++mi) {
            #pragma unroll
            for (int v = 0; v < 4; ++v) {
                int gm = bm0 + wr * 64 + mi * 16 + lg * 4 + v;
                if (gm >= NN) continue;
                #pragma unroll
                for (int ni = 0; ni < 4; ++ni) {
                    int j = cb * 128 + wc * 64 + ni * 16 + lm;
                    P[(size_t)gm * 1024 + j] = f2bf(acc[mi][ni][v]);
                }
            }
        }
    }
}

// ---- dense GEMM, fp32-x input (layer 0 only): same body, A converts on load ----
__global__ __launch_bounds__(256) void gemm_px(
        const float* __restrict__ xf,            // [N][128] fp32
        const unsigned short* __restrict__ Wt2,  // [1024][128] bf16
        unsigned short* __restrict__ P) {        // [N][1024] bf16
    int tid = threadIdx.x;
    int wid = tid >> 6, lane = tid & 63;
    int wr = wid >> 1, wc = wid & 1;
    int lm = lane & 15, lg = lane >> 4;
    int bm0 = blockIdx.x * 128;

    short8 af[4][4];
    #pragma unroll
    for (int mi = 0; mi < 4; ++mi) {
        int gr = bm0 + wr * 64 + mi * 16 + lm;
        #pragma unroll
        for (int ks = 0; ks < 4; ++ks) {
            short8 t = {};
            if (gr < NN) {
                f32x4 a0 = *(const f32x4*)(xf + (size_t)gr * DD + ks * 32 + lg * 8);
                f32x4 a1 = *(const f32x4*)(xf + (size_t)gr * DD + ks * 32 + lg * 8 + 4);
                t[0] = (short)f2bf(a0.x); t[1] = (short)f2bf(a0.y);
                t[2] = (short)f2bf(a0.z); t[3] = (short)f2bf(a0.w);
                t[4] = (short)f2bf(a1.x); t[5] = (short)f2bf(a1.y);
                t[6] = (short)f2bf(a1.z); t[7] = (short)f2bf(a1.w);
            }
            af[mi][ks] = t;
        }
    }
    for (int cb = 0; cb < 8; ++cb) {
        f32x4 acc[4][4] = {};
        #pragma unroll
        for (int ks = 0; ks < 4; ++ks) {
            short8 bfr[4];
            #pragma unroll
            for (int ni = 0; ni < 4; ++ni)
                bfr[ni] = *(const short8*)(Wt2 + (size_t)(cb * 128 + wc * 64 + ni * 16 + lm) * DD
                                           + ks * 32 + lg * 8);
            #pragma unroll
            for (int mi = 0; mi < 4; ++mi)
                #pragma unroll
                for (int ni = 0; ni < 4; ++ni)
                    acc[mi][ni] = __builtin_amdgcn_mfma_f32_16x16x32_bf16(af[mi][ks], bfr[ni], acc[mi][ni], 0, 0, 0);
        }
        #pragma unroll
        for (int mi = 0; mi < 4; ++mi) {
            #pragma unroll
            for (int v = 0; v < 4; ++v) {
                int gm = bm0 + wr * 64 + mi * 16 + lg * 4 + v;
                if (gm >= NN) continue;
                #pragma unroll
                for (int ni = 0; ni < 4; ++ni) {
                    int j = cb * 128 + wc * 64 + ni * 16 + lm;
                    P[(size_t)gm * 1024 + j] = f2bf(acc[mi][ni][v]);
                }
            }
        }
    }
}

// ---- gather: wave/node, 4 edge streams (quarter-wave), depth-3 per stream ----
// lane = q*16 + l4; stream q walks edges q, q+4, ...; lane covers 16B = cols l4*8..+7.
#define PR4(r) (((const u32x4*)(P + (size_t)(((((r).x & 0xFFFF) << 3) | ((r).x >> 16))) * DD)) + l4)
__global__ __launch_bounds__(256) void gather_p(
        const unsigned short* __restrict__ P,    // [N][8][128] bf16
        const int2* __restrict__ segd,           // [N] {start,count}
        const int2* __restrict__ edges,          // +16 zeroed slop records
        const float* __restrict__ bias,
        const unsigned short* __restrict__ hb_in,// bf16 residual (l>0)
        const float* __restrict__ xf,            // fp32 residual (l==0) or null
        unsigned short* __restrict__ hb_out,     // bf16 [N][128] (l<2)
        float* __restrict__ nf,                  // fp32 [N][128] (last layer)
        int last) {
    int tid = threadIdx.x;
    int wv = tid >> 6, lane = tid & 63;
    int q = lane >> 4, l4 = lane & 15;
    int node = blockIdx.x * 4 + wv;              // 12500*4 = 50000 exact
    int2 sd = segd[node];
    int st = sd.x, cnt = sd.y;
    int base = st + q;
    int mmax = (cnt + 3) >> 2;

    float ac[8] = {};
    int2 r0 = edges[base];
    int2 r1 = edges[base + 4];
    int2 r2 = edges[base + 8];
    u32x4 hv0 = *PR4(r0);
    u32x4 hv1 = *PR4(r1);
    for (int i = 0; i < mmax; ++i) {
        int2 r3 = edges[base + 4 * i + 12];
        u32x4 hv2 = *PR4(r2);
        if (q + 4 * i < cnt) {
            float w = __int_as_float(r0.y);
            #pragma unroll
            for (int j = 0; j < 4; ++j) {
                ac[2 * j]     += bf2f((unsigned short)(hv0[j] & 0xFFFF)) * w;
                ac[2 * j + 1] += bf2f((unsigned short)(hv0[j] >> 16)) * w;
            }
        }
        r0 = r1; r1 = r2; r2 = r3;
        hv0 = hv1; hv1 = hv2;
    }
    // combine 4 streams
    #pragma unroll
    for (int j = 0; j < 8; ++j) {
        ac[j] += __shfl_xor(ac[j], 16);
        ac[j] += __shfl_xor(ac[j], 32);
    }
    if (q == 0) {
        u32x4 hs = ((const u32x4*)(P + ((size_t)node * 8 + 7) * DD))[l4];
        f32x4 b0 = ((const f32x4*)bias)[l4 * 2];
        f32x4 b1 = ((const f32x4*)bias)[l4 * 2 + 1];
        float hp[8];
        if (xf) {
            f32x4 h0 = ((const f32x4*)xf)[(size_t)node * 32 + l4 * 2];
            f32x4 h1 = ((const f32x4*)xf)[(size_t)node * 32 + l4 * 2 + 1];
            hp[0] = h0.x; hp[1] = h0.y; hp[2] = h0.z; hp[3] = h0.w;
            hp[4] = h1.x; hp[5] = h1.y; hp[6] = h1.z; hp[7] = h1.w;
        } else {
            u32x4 hpv = ((const u32x4*)hb_in)[(size_t)node * 16 + l4];
            #pragma unroll
            for (int j = 0; j < 4; ++j) {
                hp[2 * j]     = bf2f((unsigned short)(hpv[j] & 0xFFFF));
                hp[2 * j + 1] = bf2f((unsigned short)(hpv[j] >> 16));
            }
        }
        float bb[8] = { b0.x, b0.y, b0.z, b0.w, b1.x, b1.y, b1.z, b1.w };
        float o[8];
        #pragma unroll
        for (int j = 0; j < 4; ++j) {
            o[2 * j]     = fmaxf(ac[2 * j]     + bf2f((unsigned short)(hs[j] & 0xFFFF)) + bb[2 * j],     0.f) + hp[2 * j];
            o[2 * j + 1] = fmaxf(ac[2 * j + 1] + bf2f((unsigned short)(hs[j] >> 16))    + bb[2 * j + 1], 0.f) + hp[2 * j + 1];
        }
        if (last) {
            ((f32x4*)nf)[(size_t)node * 32 + l4 * 2]     = (f32x4){o[0], o[1], o[2], o[3]};
            ((f32x4*)nf)[(size_t)node * 32 + l4 * 2 + 1] = (f32x4){o[4], o[5], o[6], o[7]};
        } else {
            u32x4 pk;
            #pragma unroll
            for (int j = 0; j < 4; ++j)
                pk[j] = (unsigned)f2bf(o[2 * j]) | ((unsigned)f2bf(o[2 * j + 1]) << 16);
            ((u32x4*)hb_out)[(size_t)node * 16 + l4] = pk;
        }
    }
}

// Parallel readout: block = 128 nodes, 8 row-streams x 32 lanes (f32x4 cols).
__global__ __launch_bounds__(256) void readout(const float* __restrict__ h,
                                               const int* __restrict__ n2g,
                                               float* __restrict__ gf) {
    int c0 = blockIdx.x * 128;
    int rg = threadIdx.x >> 5, d4 = threadIdx.x & 31;
    f32x4 acc = {0.f, 0.f, 0.f, 0.f};
    int cur = -1;
    #pragma unroll 4
    for (int it = 0; it < 16; ++it) {
        int row = c0 + it * 8 + rg;
        if (row >= NN) break;
        int g = n2g[row];
        if (g != cur) {
            if (cur >= 0) {
                atomicAdd(&gf[cur * DD + d4 * 4 + 0], acc.x);
                atomicAdd(&gf[cur * DD + d4 * 4 + 1], acc.y);
                atomicAdd(&gf[cur * DD + d4 * 4 + 2], acc.z);
                atomicAdd(&gf[cur * DD + d4 * 4 + 3], acc.w);
            }
            cur = g;
            acc = (f32x4){0.f, 0.f, 0.f, 0.f};
        }
        acc += ((const f32x4*)h)[(size_t)row * 32 + d4];
    }
    if (cur >= 0) {
        atomicAdd(&gf[cur * DD + d4 * 4 + 0], acc.x);
        atomicAdd(&gf[cur * DD + d4 * 4 + 1], acc.y);
        atomicAdd(&gf[cur * DD + d4 * 4 + 2], acc.z);
        atomicAdd(&gf[cur * DD + d4 * 4 + 3], acc.w);
    }
}

extern "C" void kernel_launch(void* const* d_in, const int* in_sizes, int n_in,
                              void* d_out, int out_size, void* d_ws, size_t ws_size,
                              hipStream_t stream) {
    const float* x      = (const float*)d_in[0];
    const int* node_in  = (const int*)d_in[1];
    const int* node_out = (const int*)d_in[2];
    const int* relation = (const int*)d_in[3];
    const float* ew     = (const float*)d_in[4];
    const int* n2g      = (const int*)d_in[5];

    float* out = (float*)d_out;
    float* gf = out;                       // [G,D]
    float* nf = out + GG * DD;             // [N,D]

    char* ws = (char*)d_ws;
    size_t off = 0;
    unsigned short* P  = (unsigned short*)(ws + off); off += (size_t)NN * 1024 * 2;   // 102.4 MB
    unsigned short* hb0 = (unsigned short*)(ws + off); off += (size_t)NN * DD * 2;    // 12.8 MB
    unsigned short* hb1 = (unsigned short*)(ws + off); off += (size_t)NN * DD * 2;    // 12.8 MB
    unsigned short* Wt2 = (unsigned short*)(ws + off); off += (size_t)3 * 1024 * DD * 2;
    float* bias = (float*)(ws + off);            off += 3 * DD * 4;
    int* counts = (int*)(ws + off);              off += (size_t)NN * 4;
    int* cursor = (int*)(ws + off);              off += (size_t)NN * 4;
    int* start  = (int*)(ws + off);              off += (size_t)NN * 4;
    int2* segd  = (int2*)(ws + off);             off += (size_t)NN * 8;
    int* bsum   = (int*)(ws + off);              off += 64 * 4;
    int2* edges = (int2*)(ws + off);             off += (size_t)(EE + 16) * 8;        // +slop

    prep_w2<<<3 * 512, 256, 0, stream>>>(
        (const float*)d_in[10], (const float*)d_in[14], (const float*)d_in[18],
        (const float*)d_in[8],  (const float*)d_in[12], (const float*)d_in[16],
        (const float*)d_in[11], (const float*)d_in[15], (const float*)d_in[19],
        (const float*)d_in[9],  (const float*)d_in[13], (const float*)d_in[17],
        Wt2, bias);

    // CSR build (node-grouped; layer-invariant)
    zero_misc<<<(2 * NN + 255) / 256, 256, 0, stream>>>(counts, (int*)(edges + EE), gf);
    hist<<<(EE + 255) / 256, 256, 0, stream>>>(node_out, counts);
    scan1<<<NB1, 256, 0, stream>>>(counts, start, bsum);
    scan2<<<1, 64, 0, stream>>>(bsum);
    scan3<<<(NN + 255) / 256, 256, 0, stream>>>(start, bsum, counts, segd);
    fill<<<(EE + 255) / 256, 256, 0, stream>>>(node_in, node_out, relation, ew,
                                               segd, cursor, edges);

    // layer 0: read x directly; layers 1,2: bf16 ping-pong hb1 -> hb0
    gemm_px<<<(NN + 127) / 128, 256, 0, stream>>>(x, Wt2, P);
    gather_p<<<NN / 4, 256, 0, stream>>>(P, segd, edges, bias, nullptr, x,
                                         hb1, nf, 0);
    gemm_pb<<<(NN + 127) / 128, 256, 0, stream>>>(hb1, Wt2 + (size_t)1024 * DD, P);
    gather_p<<<NN / 4, 256, 0, stream>>>(P, segd, edges, bias + DD, hb1, nullptr,
                                         hb0, nf, 0);
    gemm_pb<<<(NN + 127) / 128, 256, 0, stream>>>(hb0, Wt2 + (size_t)2048 * DD, P);
    gather_p<<<NN / 4, 256, 0, stream>>>(P, segd, edges, bias + 2 * DD, hb0, nullptr,
                                         nullptr, nf, 1);

    readout<<<(NN + 127) / 128, 256, 0, stream>>>(nf, n2g, gf);
}